// Round 11
// baseline (1914.536 us; speedup 1.0000x reference)
//
#include <hip/hip_runtime.h>

typedef unsigned short u16;
typedef __attribute__((ext_vector_type(8))) short short8;
typedef __attribute__((ext_vector_type(4))) float f32x4;
typedef __attribute__((ext_vector_type(4))) u16 u16x4;

#define LSEQ   1024
#define DMODEL 1024
#define NHEAD  16
#define DHEAD  64
#define DFF    4096
#define NLAYER 12
#define NVOCAB 32000

__device__ __forceinline__ u16 f2b(float f) {
  union { float f; unsigned u; } x; x.f = f;
  unsigned r = x.u + 0x7fffu + ((x.u >> 16) & 1u);   // RNE
  return (u16)(r >> 16);
}
__device__ __forceinline__ float b2f(u16 u) {
  union { unsigned u; float f; } x; x.u = ((unsigned)u) << 16; return x.f;
}

__device__ __forceinline__ f32x4 mfma16(short8 a, short8 b, f32x4 c) {
  return __builtin_amdgcn_mfma_f32_16x16x32_bf16(a, b, c, 0, 0, 0);
}

// async global->LDS, 16B per lane. LDS dest = wave-uniform base + lane*16.
__device__ __forceinline__ void gload16(const u16* g, u16* l) {
  __builtin_amdgcn_global_load_lds(
      (const __attribute__((address_space(1))) void*)g,
      (__attribute__((address_space(3))) void*)l, 16, 0, 0);
}

template<int N> __device__ __forceinline__ void waitvm() {
  if constexpr (N <= 0)       asm volatile("s_waitcnt vmcnt(0)" ::: "memory");
  else if constexpr (N == 1)  asm volatile("s_waitcnt vmcnt(1)" ::: "memory");
  else if constexpr (N == 2)  asm volatile("s_waitcnt vmcnt(2)" ::: "memory");
  else if constexpr (N == 3)  asm volatile("s_waitcnt vmcnt(3)" ::: "memory");
  else if constexpr (N == 4)  asm volatile("s_waitcnt vmcnt(4)" ::: "memory");
  else if constexpr (N == 5)  asm volatile("s_waitcnt vmcnt(5)" ::: "memory");
  else if constexpr (N == 6)  asm volatile("s_waitcnt vmcnt(6)" ::: "memory");
  else if constexpr (N == 8)  asm volatile("s_waitcnt vmcnt(8)" ::: "memory");
  else if constexpr (N == 10) asm volatile("s_waitcnt vmcnt(10)" ::: "memory");
  else                        asm volatile("s_waitcnt vmcnt(12)" ::: "memory");
}

// ---------------- embedding + positional encoding ----------------
__global__ __launch_bounds__(256) void embed_k(const int* __restrict__ tok,
    const float* __restrict__ emb, float* __restrict__ x, u16* __restrict__ xb)
{
  const int l = blockIdx.x;
  const int d0 = threadIdx.x * 4;
  const int t = tok[l];
  const float lf = (float)l;
  float o[4]; u16 obv[4];
#pragma unroll
  for (int j = 0; j < 4; ++j) {
    int d = d0 + j;
    int p = d >> 1;
    float ang = lf * powf(10000.0f, -(float)(2 * p) / 1024.0f);
    float pe = (d & 1) ? cosf(ang) : sinf(ang);
    float val = 2.0f * emb[(size_t)t * DMODEL + d] * 55.42562584220407f + pe; // sqrt(3072)
    o[j] = val; obv[j] = f2b(val);
  }
  *reinterpret_cast<float4*>(x + (size_t)l * DMODEL + d0) = make_float4(o[0], o[1], o[2], o[3]);
  u16x4 vb = { obv[0], obv[1], obv[2], obv[3] };
  *reinterpret_cast<u16x4*>(xb + (size_t)l * DMODEL + d0) = vb;
}

// ---------------- residual-add (+P f32 partials, +opt bias) + LayerNorm ----------------
__global__ __launch_bounds__(256) void ln_k(const float* __restrict__ xin,
    const float* __restrict__ ypart, int P, const float* __restrict__ ybias,
    const float* __restrict__ s, const float* __restrict__ b,
    float* __restrict__ xout, u16* __restrict__ xbout)
{
  const int row = blockIdx.x, tid = threadIdx.x;
  const int d0 = tid * 4;
  float4 xv = *reinterpret_cast<const float4*>(xin + (size_t)row * DMODEL + d0);
  float t0 = xv.x, t1 = xv.y, t2 = xv.z, t3 = xv.w;
#pragma unroll 2
  for (int p = 0; p < P; ++p) {
    float4 yv = *reinterpret_cast<const float4*>(ypart + (size_t)p * (LSEQ * DMODEL) + (size_t)row * DMODEL + d0);
    t0 += yv.x; t1 += yv.y; t2 += yv.z; t3 += yv.w;
  }
  if (ybias) {
    float4 bb = *reinterpret_cast<const float4*>(ybias + d0);
    t0 += bb.x; t1 += bb.y; t2 += bb.z; t3 += bb.w;
  }
  float sum = t0 + t1 + t2 + t3;
  float sq  = t0 * t0 + t1 * t1 + t2 * t2 + t3 * t3;
#pragma unroll
  for (int d = 1; d < 64; d <<= 1) { sum += __shfl_xor(sum, d); sq += __shfl_xor(sq, d); }
  __shared__ float ssum[4], ssq[4];
  const int wid = tid >> 6;
  if ((tid & 63) == 0) { ssum[wid] = sum; ssq[wid] = sq; }
  __syncthreads();
  sum = ssum[0] + ssum[1] + ssum[2] + ssum[3];
  sq  = ssq[0] + ssq[1] + ssq[2] + ssq[3];
  const float mu = sum * (1.0f / 1024.0f);
  const float var = sq * (1.0f / 1024.0f) - mu * mu;
  const float rstd = rsqrtf(var + 1e-5f);
  float4 sv = *reinterpret_cast<const float4*>(s + d0);
  float4 bv = *reinterpret_cast<const float4*>(b + d0);
  float o0 = (t0 - mu) * rstd * sv.x + bv.x;
  float o1 = (t1 - mu) * rstd * sv.y + bv.y;
  float o2 = (t2 - mu) * rstd * sv.z + bv.z;
  float o3 = (t3 - mu) * rstd * sv.w + bv.w;
  *reinterpret_cast<float4*>(xout + (size_t)row * DMODEL + d0) = make_float4(o0, o1, o2, o3);
  u16x4 vb = { f2b(o0), f2b(o1), f2b(o2), f2b(o3) };
  *reinterpret_cast<u16x4*>(xbout + (size_t)row * DMODEL + d0) = vb;
}

// ---------------- residual-add (+P bf16 partial planes, +opt bias) + LayerNorm ----------------
__global__ __launch_bounds__(256) void lnb_k(const float* __restrict__ xin,
    const u16* __restrict__ ypart, int P, const float* __restrict__ ybias,
    const float* __restrict__ s, const float* __restrict__ b,
    float* __restrict__ xout, u16* __restrict__ xbout)
{
  const int row = blockIdx.x, tid = threadIdx.x;
  const int d0 = tid * 4;
  float4 xv = *reinterpret_cast<const float4*>(xin + (size_t)row * DMODEL + d0);
  float t0 = xv.x, t1 = xv.y, t2 = xv.z, t3 = xv.w;
#pragma unroll 4
  for (int p = 0; p < P; ++p) {
    u16x4 yv = *reinterpret_cast<const u16x4*>(ypart + (size_t)p * (LSEQ * DMODEL) + (size_t)row * DMODEL + d0);
    t0 += b2f(yv[0]); t1 += b2f(yv[1]); t2 += b2f(yv[2]); t3 += b2f(yv[3]);
  }
  if (ybias) {
    float4 bb = *reinterpret_cast<const float4*>(ybias + d0);
    t0 += bb.x; t1 += bb.y; t2 += bb.z; t3 += bb.w;
  }
  float sum = t0 + t1 + t2 + t3;
  float sq  = t0 * t0 + t1 * t1 + t2 * t2 + t3 * t3;
#pragma unroll
  for (int d = 1; d < 64; d <<= 1) { sum += __shfl_xor(sum, d); sq += __shfl_xor(sq, d); }
  __shared__ float ssum[4], ssq[4];
  const int wid = tid >> 6;
  if ((tid & 63) == 0) { ssum[wid] = sum; ssq[wid] = sq; }
  __syncthreads();
  sum = ssum[0] + ssum[1] + ssum[2] + ssum[3];
  sq  = ssq[0] + ssq[1] + ssq[2] + ssq[3];
  const float mu = sum * (1.0f / 1024.0f);
  const float var = sq * (1.0f / 1024.0f) - mu * mu;
  const float rstd = rsqrtf(var + 1e-5f);
  float4 sv = *reinterpret_cast<const float4*>(s + d0);
  float4 bv = *reinterpret_cast<const float4*>(b + d0);
  float o0 = (t0 - mu) * rstd * sv.x + bv.x;
  float o1 = (t1 - mu) * rstd * sv.y + bv.y;
  float o2 = (t2 - mu) * rstd * sv.z + bv.z;
  float o3 = (t3 - mu) * rstd * sv.w + bv.w;
  *reinterpret_cast<float4*>(xout + (size_t)row * DMODEL + d0) = make_float4(o0, o1, o2, o3);
  u16x4 vb = { f2b(o0), f2b(o1), f2b(o2), f2b(o3) };
  *reinterpret_cast<u16x4*>(xbout + (size_t)row * DMODEL + d0) = vb;
}

// ---------------- transpose-convert: f32 in[R][C] -> bf16 out rows ----------------
__global__ __launch_bounds__(256) void tconv_k(const float* __restrict__ in, u16* __restrict__ out,
                                               int R, int C, int zper, int lstride, int obase, int zstride)
{
  __shared__ float t[64][65];
  const int rt = blockIdx.y * 64, ct = blockIdx.x * 64;
  const int z = blockIdx.z;
  in += (size_t)z * zstride;
  const int tr = threadIdx.x >> 4, tc = threadIdx.x & 15;
#pragma unroll
  for (int i = 0; i < 4; ++i) {
    int r = i * 16 + tr;
    float4 v = *reinterpret_cast<const float4*>(in + (size_t)(rt + r) * C + ct + tc * 4);
    t[r][tc * 4 + 0] = v.x; t[r][tc * 4 + 1] = v.y;
    t[r][tc * 4 + 2] = v.z; t[r][tc * 4 + 3] = v.w;
  }
  __syncthreads();
  const size_t orow0 = (size_t)(z / zper) * lstride + (size_t)(z % zper) * C + obase + ct;
#pragma unroll
  for (int i = 0; i < 4; ++i) {
    int c = i * 16 + tr;
    u16x4 o;
    o[0] = f2b(t[tc * 4 + 0][c]); o[1] = f2b(t[tc * 4 + 1][c]);
    o[2] = f2b(t[tc * 4 + 2][c]); o[3] = f2b(t[tc * 4 + 3][c]);
    *reinterpret_cast<u16x4*>(out + (orow0 + c) * R + rt + tc * 4) = o;
  }
}

// ---------------- elementwise convert f32 -> bf16 ----------------
__global__ __launch_bounds__(256) void ec_k(const float* __restrict__ in, u16* __restrict__ out)
{
  const size_t i = ((size_t)blockIdx.x * 256 + threadIdx.x) * 8;
  float4 a = *reinterpret_cast<const float4*>(in + i);
  float4 b = *reinterpret_cast<const float4*>(in + i + 4);
  short8 o;
  o[0] = f2b(a.x); o[1] = f2b(a.y); o[2] = f2b(a.z); o[3] = f2b(a.w);
  o[4] = f2b(b.x); o[5] = f2b(b.y); o[6] = f2b(b.z); o[7] = f2b(b.w);
  *reinterpret_cast<short8*>(out + i) = o;
}

// ---------------- bf16 MFMA GEMM, 3-stage counted-vmcnt pipeline ----------------
// C[M,N] = act(A[M,K] * Bt[N,K]^T + bias); grid: x = M tiles, y = N tiles, z = K split.
// Stride-aware bank swizzle: sw(row) = ((row*CPR)>>3) & (CPR-1).
// BSRC 0: A and B via global_load_lds into 3 slots, counted vmcnt (T4) + swizzle (T2).
// BSRC 1: f32 B^T reg-staged fallback (BK=32, BN=128), classic loop (slot 0 only).
// BSRC 2: A = relu(plane0 + plane1 + bias) from bf16 partial planes (bias = f32[K]),
//         reg-staged 1 tile ahead, swizzled ds_write 2 slots ahead; B via gloadlds.
// OUTMODE: 0 = f32 (KSPLIT>1: partial plane per z); 1 = bf16; 2 = QKV triple (q pre-scaled 1/32);
//          3 = bf16 partial plane per z (KSPLIT>1)
template<int BM, int BN, int BK, int BSRC, bool BIAS, bool RELU, int OUTMODE, int KSPLIT>
__global__ __launch_bounds__(256) void gemm_bt(
    const u16* __restrict__ A, int lda,
    const void* __restrict__ Bp, int ldb,
    const float* __restrict__ bias,
    void* __restrict__ Cv, int ldc, int Ktot)
{
  constexpr int CPR = BK / 8;            // 16B chunks per row
  constexpr int SWM = CPR - 1;
  constexpr int LA = (BM * CPR) / 256;   // A loads/thread per K-tile
  constexpr int LB = (BN * CPR) / 256;   // B loads/thread per K-tile
  constexpr int LT = LA + LB;
  __shared__ u16 As[3][BM * BK];
  __shared__ u16 Bs[3][BN * BK];
  const int tid = threadIdx.x, lane = tid & 63, wid = tid >> 6;
  // chunked XCD swizzle on (x,y) (bijective: gx*gy is a multiple of 8 in all uses)
  const int nwg = gridDim.x * gridDim.y;
  const int flat = blockIdx.y * gridDim.x + blockIdx.x;
  const int qq = nwg >> 3;
  const int ni = (flat & 7) * qq + (flat >> 3);
  const int m0 = (ni % gridDim.x) * BM, n0 = (ni / gridDim.x) * BN;
  const int kbase = (KSPLIT > 1) ? blockIdx.z * (Ktot / KSPLIT) : 0;
  const int klen  = (KSPLIT > 1) ? (Ktot / KSPLIT) : Ktot;
  constexpr int FM = BM / 32, FN = BN / 32;
  constexpr int KS = BK / 32;
  const int wm = (wid >> 1) * (BM / 2), wn = (wid & 1) * (BN / 2);
  f32x4 acc[FM][FN] = {};

  if constexpr (BSRC == 0) {
    const u16* Bt = (const u16*)Bp;
    auto stage = [&](int slot, int k0) {
#pragma unroll
      for (int i = 0; i < LA; ++i) {
        int c = i * 256 + tid;
        int row = c / CPR, p0 = c % CPR;
        int part = p0 ^ (((row * CPR) >> 3) & SWM);
        gload16(A + (size_t)(m0 + row) * lda + k0 + part * 8,
                &As[slot][(i * 256 + wid * 64) * 8]);
      }
#pragma unroll
      for (int i = 0; i < LB; ++i) {
        int c = i * 256 + tid;
        int row = c / CPR, p0 = c % CPR;
        int part = p0 ^ (((row * CPR) >> 3) & SWM);
        gload16(Bt + (size_t)(n0 + row) * ldb + k0 + part * 8,
                &Bs[slot][(i * 256 + wid * 64) * 8]);
      }
    };

    const int NT = klen / BK;
    stage(0, kbase);
    stage(1, kbase + BK);
    waitvm<LT>();                        // tile 0 landed, tile 1 in flight
    __builtin_amdgcn_s_barrier();
    asm volatile("" ::: "memory");

    int cur = 0, stg = 2;
    for (int t = 0; t < NT; ++t) {
      const bool more = (t + 2 < NT);
      if (more) stage(stg, kbase + (t + 2) * BK);      // tile t+2 issued; stays in flight
      asm volatile("" ::: "memory");
      short8 a[KS][FM], b[KS][FN];
#pragma unroll
      for (int ks = 0; ks < KS; ++ks) {
#pragma unroll
        for (int fm = 0; fm < FM; ++fm) {
          int row = wm + fm * 16 + (lane & 15);
          int pidx = (ks * 4 + (lane >> 4)) ^ (((row * CPR) >> 3) & SWM);
          a[ks][fm] = *reinterpret_cast<const short8*>(&As[cur][row * BK + pidx * 8]);
        }
#pragma unroll
        for (int fn = 0; fn < FN; ++fn) {
          int row = wn + fn * 16 + (lane & 15);
          int pidx = (ks * 4 + (lane >> 4)) ^ (((row * CPR) >> 3) & SWM);
          b[ks][fn] = *reinterpret_cast<const short8*>(&Bs[cur][row * BK + pidx * 8]);
        }
      }
#pragma unroll
      for (int ks = 0; ks < KS; ++ks)
#pragma unroll
        for (int fm = 0; fm < FM; ++fm)
#pragma unroll
          for (int fn = 0; fn < FN; ++fn)
            acc[fm][fn] = mfma16(a[ks][fm], b[ks][fn], acc[fm][fn]);
      if (more) waitvm<LT>(); else waitvm<0>();
      __builtin_amdgcn_s_barrier();
      asm volatile("" ::: "memory");
      cur = (cur == 2) ? 0 : cur + 1;
      stg = (stg == 2) ? 0 : stg + 1;
    }
  } else if constexpr (BSRC == 2) {
    // fused FF2: A = relu(P0 + P1 + bias) reg-staged; B via gloadlds. NT >= 3 assumed.
    const u16* Bt = (const u16*)Bp;
    const u16* P0 = A;
    const u16* P1 = A + (size_t)LSEQ * lda;
    short8 rA[LA];
    auto loadA = [&](int k0) {
#pragma unroll
      for (int i = 0; i < LA; ++i) {
        int c = i * 256 + tid;
        int row = c / CPR, p0c = c % CPR;
        int part = p0c ^ (((row * CPR) >> 3) & SWM);
        size_t off = (size_t)(m0 + row) * lda + k0 + part * 8;
        short8 a0 = *reinterpret_cast<const short8*>(&P0[off]);
        short8 a1 = *reinterpret_cast<const short8*>(&P1[off]);
        float4 bb0 = *reinterpret_cast<const float4*>(&bias[k0 + part * 8]);
        float4 bb1 = *reinterpret_cast<const float4*>(&bias[k0 + part * 8 + 4]);
        short8 o;
        o[0] = (short)f2b(fmaxf(b2f((u16)a0[0]) + b2f((u16)a1[0]) + bb0.x, 0.0f));
        o[1] = (short)f2b(fmaxf(b2f((u16)a0[1]) + b2f((u16)a1[1]) + bb0.y, 0.0f));
        o[2] = (short)f2b(fmaxf(b2f((u16)a0[2]) + b2f((u16)a1[2]) + bb0.z, 0.0f));
        o[3] = (short)f2b(fmaxf(b2f((u16)a0[3]) + b2f((u16)a1[3]) + bb0.w, 0.0f));
        o[4] = (short)f2b(fmaxf(b2f((u16)a0[4]) + b2f((u16)a1[4]) + bb1.x, 0.0f));
        o[5] = (short)f2b(fmaxf(b2f((u16)a0[5]) + b2f((u16)a1[5]) + bb1.y, 0.0f));
        o[6] = (short)f2b(fmaxf(b2f((u16)a0[6]) + b2f((u16)a1[6]) + bb1.z, 0.0f));
        o[7] = (short)f2b(fmaxf(b2f((u16)a0[7]) + b2f((u16)a1[7]) + bb1.w, 0.0f));
        rA[i] = o;
      }
    };
    auto writeA = [&](int slot) {
#pragma unroll
      for (int i = 0; i < LA; ++i) {
        int c = i * 256 + tid;
        *reinterpret_cast<short8*>(&As[slot][c * 8]) = rA[i];
      }
    };
    auto stageB = [&](int slot, int k0) {
#pragma unroll
      for (int i = 0; i < LB; ++i) {
        int c = i * 256 + tid;
        int row = c / CPR, p0c = c % CPR;
        int part = p0c ^ (((row * CPR) >> 3) & SWM);
        gload16(Bt + (size_t)(n0 + row) * ldb + k0 + part * 8,
                &Bs[slot][(i * 256 + wid * 64) * 8]);
      }
    };
    const int NT = klen / BK;
    loadA(kbase);          writeA(0);
    loadA(kbase + BK);     writeA(1);
    stageB(0, kbase);
    stageB(1, kbase + BK);
    loadA(kbase + 2 * BK);                 // rA holds A(2), in flight
    waitvm<8>();                           // B(0),B(1) landed; A(2) may fly
    asm volatile("s_waitcnt lgkmcnt(0)" ::: "memory");
    __builtin_amdgcn_s_barrier();
    asm volatile("" ::: "memory");

    int cur = 0, stg = 2;
    for (int t = 0; t < NT; ++t) {
      const bool more = (t + 2 < NT);
      if (more) writeA(stg);               // compiler inserts vmcnt for rA deps
      if (t + 3 < NT) loadA(kbase + (t + 3) * BK);
      if (more) stageB(stg, kbase + (t + 2) * BK);
      asm volatile("" ::: "memory");
      short8 a[KS][FM], b[KS][FN];
#pragma unroll
      for (int ks = 0; ks < KS; ++ks) {
#pragma unroll
        for (int fm = 0; fm < FM; ++fm) {
          int row = wm + fm * 16 + (lane & 15);
          int pidx = (ks * 4 + (lane >> 4)) ^ (((row * CPR) >> 3) & SWM);
          a[ks][fm] = *reinterpret_cast<const short8*>(&As[cur][row * BK + pidx * 8]);
        }
#pragma unroll
        for (int fn = 0; fn < FN; ++fn) {
          int row = wn + fn * 16 + (lane & 15);
          int pidx = (ks * 4 + (lane >> 4)) ^ (((row * CPR) >> 3) & SWM);
          b[ks][fn] = *reinterpret_cast<const short8*>(&Bs[cur][row * BK + pidx * 8]);
        }
      }
#pragma unroll
      for (int ks = 0; ks < KS; ++ks)
#pragma unroll
        for (int fm = 0; fm < FM; ++fm)
#pragma unroll
          for (int fn = 0; fn < FN; ++fn)
            acc[fm][fn] = mfma16(a[ks][fm], b[ks][fn], acc[fm][fn]);
      // B(t+1) must land before the barrier (read next iter); A(t+3)+B(t+2) stay in flight
      if (more) waitvm<10>(); else waitvm<0>();
      asm volatile("s_waitcnt lgkmcnt(0)" ::: "memory");   // ds_writes visible after barrier
      __builtin_amdgcn_s_barrier();
      asm volatile("" ::: "memory");
      cur = (cur == 2) ? 0 : cur + 1;
      stg = (stg == 2) ? 0 : stg + 1;
    }
  } else {                       // f32 B^T fallback: BK=32, BN=128, slot 0 only
    const float* Bf = (const float*)Bp;
    for (int k0 = 0; k0 < Ktot; k0 += BK) {
#pragma unroll
      for (int i = 0; i < LA; ++i) {
        int c = i * 256 + tid;
        int row = c / CPR, part = c % CPR;
        gload16(A + (size_t)(m0 + row) * lda + k0 + part * 8,
                &As[0][(i * 256 + wid * 64) * 8]);
      }
      {
        int row = tid >> 1, kh = (tid & 1) * 16;
        const float* src = Bf + (size_t)(n0 + row) * ldb + k0 + kh;
        float4 v0 = *reinterpret_cast<const float4*>(src);
        float4 v1 = *reinterpret_cast<const float4*>(src + 4);
        float4 v2 = *reinterpret_cast<const float4*>(src + 8);
        float4 v3 = *reinterpret_cast<const float4*>(src + 12);
        short8 p0, p1;
        p0[0] = f2b(v0.x); p0[1] = f2b(v0.y); p0[2] = f2b(v0.z); p0[3] = f2b(v0.w);
        p0[4] = f2b(v1.x); p0[5] = f2b(v1.y); p0[6] = f2b(v1.z); p0[7] = f2b(v1.w);
        p1[0] = f2b(v2.x); p1[1] = f2b(v2.y); p1[2] = f2b(v2.z); p1[3] = f2b(v2.w);
        p1[4] = f2b(v3.x); p1[5] = f2b(v3.y); p1[6] = f2b(v3.z); p1[7] = f2b(v3.w);
        *reinterpret_cast<short8*>(&Bs[0][row * BK + kh])     = p0;
        *reinterpret_cast<short8*>(&Bs[0][row * BK + kh + 8]) = p1;
      }
      __syncthreads();
      short8 a[KS][FM], b[KS][FN];
#pragma unroll
      for (int ks = 0; ks < KS; ++ks) {
#pragma unroll
        for (int fm = 0; fm < FM; ++fm) {
          int row = wm + fm * 16 + (lane & 15);
          a[ks][fm] = *reinterpret_cast<const short8*>(&As[0][row * BK + (ks * 4 + (lane >> 4)) * 8]);
        }
#pragma unroll
        for (int fn = 0; fn < FN; ++fn) {
          int row = wn + fn * 16 + (lane & 15);
          b[ks][fn] = *reinterpret_cast<const short8*>(&Bs[0][row * BK + (ks * 4 + (lane >> 4)) * 8]);
        }
      }
#pragma unroll
      for (int ks = 0; ks < KS; ++ks)
#pragma unroll
        for (int fm = 0; fm < FM; ++fm)
#pragma unroll
          for (int fn = 0; fn < FN; ++fn)
            acc[fm][fn] = mfma16(a[ks][fm], b[ks][fn], acc[fm][fn]);
      __syncthreads();
    }
  }

  // ---- epilogue ----
  const size_t pbase = (KSPLIT > 1) ? (size_t)blockIdx.z * gridDim.x * BM * ldc : 0;
#pragma unroll
  for (int fm = 0; fm < FM; ++fm) {
#pragma unroll
    for (int fn = 0; fn < FN; ++fn) {
#pragma unroll
      for (int r = 0; r < 4; ++r) {
        int row = m0 + wm + fm * 16 + (lane >> 4) * 4 + r;
        int col = n0 + wn + fn * 16 + (lane & 15);
        float val = acc[fm][fn][r];
        if (BIAS) val += bias[col];
        if (RELU) val = fmaxf(val, 0.0f);
        if (OUTMODE == 0) {
          ((float*)Cv)[pbase + (size_t)row * ldc + col] = val;
        } else if (OUTMODE == 1) {
          ((u16*)Cv)[(size_t)row * ldc + col] = f2b(val);
        } else if (OUTMODE == 3) {
          ((u16*)Cv)[pbase + (size_t)row * ldc + col] = f2b(val);
        } else {
          int sel = col >> 10, cc = col & 1023;
          if (sel == 0) val *= 0.03125f;          // pre-scale q by 1/sqrt(d_model)
          ((u16*)Cv)[(size_t)sel * (LSEQ * DMODEL) + (size_t)row * DMODEL + cc] = f2b(val);
        }
      }
    }
  }
}

// ---------------- causal flash attention, KVBLK=64, async reg-staged K/V (T14) ----------------
// FUSE=1: q points at the QKV split-K bf16 partial planes sp [2][L][3072];
//         q/k/v combined (plane0+plane1, q scaled 1/32) at LDS-write time.
// FUSE=0: q/k/v separate [L][1024] bf16 buffers (q pre-scaled).
template<int FUSE>
__global__ __launch_bounds__(256) void attn_k(const u16* __restrict__ q,
    const u16* __restrict__ kmat, const u16* __restrict__ v, u16* __restrict__ o)
{
  __shared__ u16 Ks[64][72];
  __shared__ u16 Vt[64][72];
  __shared__ u16 Pl[4][16][72];
  const int tid = threadIdx.x, lane = tid & 63, wid = tid >> 6;
  const int h = blockIdx.y, qt = blockIdx.x;
  const int qw0 = qt * 64 + wid * 16;
  const int qrow = qw0 + (lane & 15);
  const size_t PLQ = (size_t)LSEQ * 3072;
  short8 aq0, aq1;
  if constexpr (FUSE) {
    const u16* qp = q + (size_t)qrow * 3072 + h * DHEAD + (lane >> 4) * 8;
    short8 a0 = *reinterpret_cast<const short8*>(qp);
    short8 b0 = *reinterpret_cast<const short8*>(qp + PLQ);
    short8 a1 = *reinterpret_cast<const short8*>(qp + 32);
    short8 b1 = *reinterpret_cast<const short8*>(qp + 32 + PLQ);
#pragma unroll
    for (int j = 0; j < 8; ++j) {
      aq0[j] = (short)f2b((b2f((u16)a0[j]) + b2f((u16)b0[j])) * 0.03125f);
      aq1[j] = (short)f2b((b2f((u16)a1[j]) + b2f((u16)b1[j])) * 0.03125f);
    }
  } else {
    aq0 = *reinterpret_cast<const short8*>(q + (size_t)qrow * DMODEL + h * DHEAD + (lane >> 4) * 8);
    aq1 = *reinterpret_cast<const short8*>(q + (size_t)qrow * DMODEL + h * DHEAD + 32 + (lane >> 4) * 8);
  }
  float m_run[4], l_run[4];
  f32x4 oacc[4] = {};
#pragma unroll
  for (int r = 0; r < 4; ++r) { m_run[r] = -1e30f; l_run[r] = 0.0f; }
  const int kvend = qt * 64 + 64;

  const int kvi = tid >> 2, c16 = (tid & 3) * 16;
  short8 kr0, kr1, vr0, vr1;
  short8 kr0b, kr1b, vr0b, vr1b;
  auto loadregs = [&](int kv0) {
    if constexpr (FUSE) {
      const u16* kp = q + (size_t)(kv0 + kvi) * 3072 + 1024 + h * DHEAD + c16;
      kr0  = *reinterpret_cast<const short8*>(kp);
      kr1  = *reinterpret_cast<const short8*>(kp + 8);
      kr0b = *reinterpret_cast<const short8*>(kp + PLQ);
      kr1b = *reinterpret_cast<const short8*>(kp + 8 + PLQ);
      const u16* vp = q + (size_t)(kv0 + kvi) * 3072 + 2048 + h * DHEAD + c16;
      vr0  = *reinterpret_cast<const short8*>(vp);
      vr1  = *reinterpret_cast<const short8*>(vp + 8);
      vr0b = *reinterpret_cast<const short8*>(vp + PLQ);
      vr1b = *reinterpret_cast<const short8*>(vp + 8 + PLQ);
    } else {
      const u16* kp = kmat + (size_t)(kv0 + kvi) * DMODEL + h * DHEAD + c16;
      kr0 = *reinterpret_cast<const short8*>(kp);
      kr1 = *reinterpret_cast<const short8*>(kp + 8);
      const u16* vp = v + (size_t)(kv0 + kvi) * DMODEL + h * DHEAD + c16;
      vr0 = *reinterpret_cast<const short8*>(vp);
      vr1 = *reinterpret_cast<const short8*>(vp + 8);
    }
  };
  loadregs(0);

  for (int kv0 = 0; kv0 < kvend; kv0 += 64) {
    __syncthreads();
    if constexpr (FUSE) {
      short8 ko0, ko1;
#pragma unroll
      for (int j = 0; j < 8; ++j) {
        ko0[j] = (short)f2b(b2f((u16)kr0[j]) + b2f((u16)kr0b[j]));
        ko1[j] = (short)f2b(b2f((u16)kr1[j]) + b2f((u16)kr1b[j]));
      }
      *reinterpret_cast<short8*>(&Ks[kvi][c16])     = ko0;
      *reinterpret_cast<short8*>(&Ks[kvi][c16 + 8]) = ko1;
#pragma unroll
      for (int j = 0; j < 8; ++j) {
        Vt[c16 + j][kvi]     = f2b(b2f((u16)vr0[j]) + b2f((u16)vr0b[j]));
        Vt[c16 + 8 + j][kvi] = f2b(b2f((u16)vr1[j]) + b2f((u16)vr1b[j]));
      }
    } else {
      *reinterpret_cast<short8*>(&Ks[kvi][c16])     = kr0;
      *reinterpret_cast<short8*>(&Ks[kvi][c16 + 8]) = kr1;
#pragma unroll
      for (int j = 0; j < 8; ++j) { Vt[c16 + j][kvi] = (u16)vr0[j]; Vt[c16 + 8 + j][kvi] = (u16)vr1[j]; }
    }
    __syncthreads();
    if (kv0 + 64 < kvend) loadregs(kv0 + 64);

    float sm[4][4];
#pragma unroll
    for (int t2 = 0; t2 < 4; ++t2) {
      short8 bk0 = *reinterpret_cast<const short8*>(&Ks[t2 * 16 + (lane & 15)][(lane >> 4) * 8]);
      short8 bk1 = *reinterpret_cast<const short8*>(&Ks[t2 * 16 + (lane & 15)][32 + (lane >> 4) * 8]);
      f32x4 s4 = {};
      s4 = mfma16(aq0, bk0, s4);
      s4 = mfma16(aq1, bk1, s4);
#pragma unroll
      for (int r = 0; r < 4; ++r) {
        int rowg = qw0 + (lane >> 4) * 4 + r;
        int colg = kv0 + t2 * 16 + (lane & 15);
        sm[t2][r] = (colg <= rowg) ? s4[r] : -1e30f;
      }
    }
    float alpha[4], p[4][4];
#pragma unroll
    for (int r = 0; r < 4; ++r) {
      float mx = fmaxf(fmaxf(sm[0][r], sm[1][r]), fmaxf(sm[2][r], sm[3][r]));
#pragma unroll
      for (int d = 1; d < 16; d <<= 1) mx = fmaxf(mx, __shfl_xor(mx, d));
      float mn = fmaxf(m_run[r], mx);
      alpha[r] = __expf(m_run[r] - mn);
      float ps = 0.0f;
#pragma unroll
      for (int t2 = 0; t2 < 4; ++t2) { p[t2][r] = __expf(sm[t2][r] - mn); ps += p[t2][r]; }
#pragma unroll
      for (int d = 1; d < 16; d <<= 1) ps += __shfl_xor(ps, d);
      l_run[r] = l_run[r] * alpha[r] + ps;
      m_run[r] = mn;
    }
#pragma unroll
    for (int fn = 0; fn < 4; ++fn) {
      f32x4 t = oacc[fn];
      t[0] *= alpha[0]; t[1] *= alpha[1]; t[2] *= alpha[2]; t[3] *= alpha[3];
      oacc[fn] = t;
    }
#pragma unroll
    for (int r = 0; r < 4; ++r) {
      int rit = (lane >> 4) * 4 + r;
#pragma unroll
      for (int t2 = 0; t2 < 4; ++t2)
        Pl[wid][rit][t2 * 16 + (lane & 15)] = f2b(p[t2][r]);
    }
    short8 pa0 = *reinterpret_cast<const short8*>(&Pl[wid][lane & 15][(lane >> 4) * 8]);
    short8 pa1 = *reinterpret_cast<const short8*>(&Pl[wid][lane & 15][32 + (lane >> 4) * 8]);
#pragma unroll
    for (int fn = 0; fn < 4; ++fn) {
      short8 bv0 = *reinterpret_cast<const short8*>(&Vt[fn * 16 + (lane & 15)][(lane >> 4) * 8]);
      short8 bv1 = *reinterpret_cast<const short8*>(&Vt[fn * 16 + (lane & 15)][32 + (lane >> 4) * 8]);
      oacc[fn] = mfma16(pa0, bv0, oacc[fn]);
      oacc[fn] = mfma16(pa1, bv1, oacc[fn]);
    }
  }
#pragma unroll
  for (int fn = 0; fn < 4; ++fn) {
#pragma unroll
    for (int r = 0; r < 4; ++r) {
      int row = qw0 + (lane >> 4) * 4 + r;
      float val = oacc[fn][r] / l_run[r];
      o[(size_t)row * DMODEL + h * DHEAD + fn * 16 + (lane & 15)] = f2b(val);
    }
  }
}

// ---------------- launch ----------------
extern "C" void kernel_launch(void* const* d_in, const int* in_sizes, int n_in,
                              void* d_out, int out_size, void* d_ws, size_t ws_size,
                              hipStream_t stream) {
  (void)in_sizes; (void)n_in; (void)out_size;
  const int*   tok    = (const int*)d_in[0];
  const float* emb    = (const float*)d_in[1];
  const float* finalb = (const float*)d_in[2];
  const float* Wq     = (const float*)d_in[3];
  const float* Wk     = (const float*)d_in[4];
  const float* Wv     = (const float*)d_in[5];
  const float* Wo     = (const float*)d_in[6];
  const float* ln1s   = (const float*)d_in[7];
  const float* ln1b   = (const float*)d_in[8];
  const float* W1     = (const float*)d_in[9];
  const float* b1     = (const float*)d_in[10];
  const float* W2     = (const float*)d_in[11];
  const float* b2     = (const float*)d_in[12];
  const float* ln2s   = (const float*)d_in[13];
  const float* ln2b   = (const float*)d_in[14];
  float* out = (float*)d_out;

  // workspace: activations
  float* x   = (float*)d_ws;                       // 4 MiB
  float* y   = x + LSEQ * DMODEL;                  // 4 MiB (scratch)
  u16* xb    = (u16*)(y + LSEQ * DMODEL);
  u16* qb    = xb + LSEQ * DMODEL;                 // fallback q/k/v; fused: FF2 partial planes
  u16* kb    = qb + LSEQ * DMODEL;
  u16* vb    = kb + LSEQ * DMODEL;
  u16* ob    = vb + LSEQ * DMODEL;
  u16* h1    = ob + LSEQ * DMODEL;                 // 8 MiB (fallback only)
  u16* wbase = h1 + LSEQ * DFF;
  u16* ff2p  = qb;                                 // 8 contiguous bf16 planes (qb..h1 end, 16 MiB)

  const size_t eQKV = (size_t)3 * DMODEL * DMODEL;
  const size_t eWO  = (size_t)DMODEL * DMODEL;
  const size_t eW1  = (size_t)DFF * DMODEL;
  const size_t eW2  = (size_t)DMODEL * DFF;
  const size_t perL = eQKV + eWO + eW1 + eW2;
  const size_t eEMB = (size_t)NVOCAB * DMODEL;
  const size_t eSP  = (size_t)2 * LSEQ * DFF;        // split-K bf16 partials (16 MiB)
  const size_t actE = (size_t)(wbase - (u16*)d_ws);
  const size_t bigNeed = (actE + NLAYER * perL + eEMB + eSP) * 2;
  const size_t midNeed = (actE + perL + eEMB) * 2;
  const int mode = ws_size >= bigNeed ? 2 : (ws_size >= midNeed ? 1 : 0);
  const int WL = (mode == 2) ? NLAYER : 1;

  u16* qkvT = wbase;
  u16* woT  = qkvT + WL * eQKV;
  u16* w1T  = woT  + WL * eWO;
  u16* w2T  = w1T  + WL * eW1;
  u16* embT = w2T  + WL * eW2;
  u16* sp   = embT + eEMB;                           // bf16 split-K partial planes

  if (mode == 2) {
    tconv_k<<<dim3(1, 16, 192), 256, 0, stream>>>(Wq, qkvT, DMODEL, DHEAD, 16, 3 * DMODEL, 0,    DMODEL * DHEAD);
    tconv_k<<<dim3(1, 16, 192), 256, 0, stream>>>(Wk, qkvT, DMODEL, DHEAD, 16, 3 * DMODEL, 1024, DMODEL * DHEAD);
    tconv_k<<<dim3(1, 16, 192), 256, 0, stream>>>(Wv, qkvT, DMODEL, DHEAD, 16, 3 * DMODEL, 2048, DMODEL * DHEAD);
    tconv_k<<<dim3(16, 16, 12), 256, 0, stream>>>(Wo, woT, DMODEL, DMODEL, 1, DMODEL, 0, DMODEL * DMODEL);
    tconv_k<<<dim3(64, 16, 12), 256, 0, stream>>>(W1, w1T, DMODEL, DFF, 1, DFF, 0, DMODEL * DFF);
    tconv_k<<<dim3(16, 64, 12), 256, 0, stream>>>(W2, w2T, DFF, DMODEL, 1, DMODEL, 0, DFF * DMODEL);
    ec_k<<<(NVOCAB * DMODEL) / 2048, 256, 0, stream>>>(emb, embT);
  } else if (mode == 1) {
    ec_k<<<(NVOCAB * DMODEL) / 2048, 256, 0, stream>>>(emb, embT);
  }

  embed_k<<<LSEQ, 256, 0, stream>>>(tok, emb, x, xb);

  for (int l = 0; l < NLAYER; ++l) {
    const float* wq  = Wq + (size_t)l * NHEAD * DMODEL * DHEAD;
    const float* wk  = Wk + (size_t)l * NHEAD * DMODEL * DHEAD;
    const float* wv  = Wv + (size_t)l * NHEAD * DMODEL * DHEAD;
    const float* wo  = Wo + (size_t)l * DMODEL * DMODEL;
    const float* w1  = W1 + (size_t)l * DMODEL * DFF;
    const float* b1l = b1 + (size_t)l * DFF;
    const float* w2  = W2 + (size_t)l * DFF * DMODEL;
    const float* b2l = b2 + (size_t)l * DMODEL;
    u16* qkvTl = qkvT + (mode == 2 ? (size_t)l * eQKV : 0);
    u16* woTl  = woT  + (mode == 2 ? (size_t)l * eWO  : 0);
    u16* w1Tl  = w1T  + (mode == 2 ? (size_t)l * eW1  : 0);
    u16* w2Tl  = w2T  + (mode == 2 ? (size_t)l * eW2  : 0);

    if (mode < 2) {
      tconv_k<<<dim3(1, 16, 16), 256, 0, stream>>>(wq, qkvTl, DMODEL, DHEAD, 16, 0, 0,    DMODEL * DHEAD);
      tconv_k<<<dim3(1, 16, 16), 256, 0, stream>>>(wk, qkvTl, DMODEL, DHEAD, 16, 0, 1024, DMODEL * DHEAD);
      tconv_k<<<dim3(1, 16, 16), 256, 0, stream>>>(wv, qkvTl, DMODEL, DHEAD, 16, 0, 2048, DMODEL * DHEAD);
      tconv_k<<<dim3(16, 16, 1), 256, 0, stream>>>(wo, woTl, DMODEL, DMODEL, 1, 0, 0, 0);
      tconv_k<<<dim3(64, 16, 1), 256, 0, stream>>>(w1, w1Tl, DMODEL, DFF, 1, 0, 0, 0);
      tconv_k<<<dim3(16, 64, 1), 256, 0, stream>>>(w2, w2Tl, DFF, DMODEL, 1, 0, 0, 0);
    }

    if (mode == 2) {
      // QKV: 128x128 BK32 split-K2 (384 blocks), bf16 partials -> sp
      gemm_bt<128, 128, 32, 0, false, false, 3, 2><<<dim3(8, 24, 2), 256, 0, stream>>>(
          xb, DMODEL, qkvTl, DMODEL, nullptr, sp, 3 * DMODEL, DMODEL);
      // attention reads the partial planes directly (fused reduce + q-scale)
      attn_k<1><<<dim3(16, 16), 256, 0, stream>>>(sp, nullptr, nullptr, ob);
      // Wo: 128x128 BK32 split-K8 (512 blocks), bf16 partials -> sp (QKV planes dead)
      gemm_bt<128, 128, 32, 0, false, false, 3, 8><<<dim3(8, 8, 8), 256, 0, stream>>>(
          ob, DMODEL, woTl, DMODEL, nullptr, sp, DMODEL, DMODEL);
      lnb_k<<<LSEQ, 256, 0, stream>>>(x, sp, 8, nullptr,
          ln1s + (size_t)l * DMODEL, ln1b + (size_t)l * DMODEL, x, xb);
      // FF1: 128x128 BK32 split-K2 (512 blocks), bf16 partials -> sp (no bias/relu yet)
      gemm_bt<128, 128, 32, 0, false, false, 3, 2><<<dim3(8, 32, 2), 256, 0, stream>>>(
          xb, DMODEL, w1Tl, DMODEL, nullptr, sp, DFF, DMODEL);
      // FF2 fused: A = relu(sp0+sp1+b1) staged on the fly; split-K8 -> ff2p (8 planes)
      gemm_bt<128, 128, 32, 2, false, false, 3, 8><<<dim3(8, 8, 8), 256, 0, stream>>>(
          sp, DFF, w2Tl, DFF, b1l, ff2p, DMODEL, DFF);
      lnb_k<<<LSEQ, 256, 0, stream>>>(x, ff2p, 8, b2l,
          ln2s + (size_t)l * DMODEL, ln2b + (size_t)l * DMODEL, x, xb);
    } else {
      gemm_bt<64, 64, 64, 0, false, false, 2, 1><<<dim3(16, 48), 256, 0, stream>>>(
          xb, DMODEL, qkvTl, DMODEL, nullptr, qb, DMODEL, DMODEL);
      attn_k<0><<<dim3(16, 16), 256, 0, stream>>>(qb, kb, vb, ob);
      gemm_bt<64, 64, 64, 0, false, false, 0, 2><<<dim3(16, 16, 2), 256, 0, stream>>>(
          ob, DMODEL, woTl, DMODEL, nullptr, (float*)h1, DMODEL, DMODEL);
      ln_k<<<LSEQ, 256, 0, stream>>>(x, (float*)h1, 2, nullptr,
          ln1s + (size_t)l * DMODEL, ln1b + (size_t)l * DMODEL, x, xb);
      gemm_bt<64, 64, 64, 0, true, true, 1, 1><<<dim3(16, 64), 256, 0, stream>>>(
          xb, DMODEL, w1Tl, DMODEL, b1l, h1, DFF, DMODEL);
      gemm_bt<64, 64, 64, 0, false, false, 0, 2><<<dim3(16, 16, 2), 256, 0, stream>>>(
          h1, DFF, w2Tl, DFF, nullptr, (float*)qb, DMODEL, DFF);
      ln_k<<<LSEQ, 256, 0, stream>>>(x, (float*)qb, 2, b2l,
          ln2s + (size_t)l * DMODEL, ln2b + (size_t)l * DMODEL, x, xb);
    }
  }

  // logits = x @ emb^T + final_b  (128x128 BK=32, 48KB LDS, 2000 blocks)
  if (mode >= 1) {
    gemm_bt<128, 128, 32, 0, true, false, 0, 1><<<dim3(8, 250), 256, 0, stream>>>(
        xb, DMODEL, embT, DMODEL, finalb, out, NVOCAB, DMODEL);
  } else {
    gemm_bt<128, 128, 32, 1, true, false, 0, 1><<<dim3(8, 250), 256, 0, stream>>>(
        xb, DMODEL, emb, DMODEL, finalb, out, NVOCAB, DMODEL);
  }
}

// Round 12
// 1773.601 us; speedup vs baseline: 1.0795x; 1.0795x over previous
//
#include <hip/hip_runtime.h>

typedef unsigned short u16;
typedef __attribute__((ext_vector_type(8))) short short8;
typedef __attribute__((ext_vector_type(4))) float f32x4;
typedef __attribute__((ext_vector_type(4))) u16 u16x4;

#define LSEQ   1024
#define DMODEL 1024
#define NHEAD  16
#define DHEAD  64
#define DFF    4096
#define NLAYER 12
#define NVOCAB 32000

__device__ __forceinline__ u16 f2b(float f) {
  union { float f; unsigned u; } x; x.f = f;
  unsigned r = x.u + 0x7fffu + ((x.u >> 16) & 1u);   // RNE
  return (u16)(r >> 16);
}
__device__ __forceinline__ float b2f(u16 u) {
  union { unsigned u; float f; } x; x.u = ((unsigned)u) << 16; return x.f;
}

__device__ __forceinline__ f32x4 mfma16(short8 a, short8 b, f32x4 c) {
  return __builtin_amdgcn_mfma_f32_16x16x32_bf16(a, b, c, 0, 0, 0);
}

// async global->LDS, 16B per lane. LDS dest = wave-uniform base + lane*16.
__device__ __forceinline__ void gload16(const u16* g, u16* l) {
  __builtin_amdgcn_global_load_lds(
      (const __attribute__((address_space(1))) void*)g,
      (__attribute__((address_space(3))) void*)l, 16, 0, 0);
}

template<int N> __device__ __forceinline__ void waitvm() {
  if constexpr (N <= 0)      asm volatile("s_waitcnt vmcnt(0)" ::: "memory");
  else if constexpr (N == 1) asm volatile("s_waitcnt vmcnt(1)" ::: "memory");
  else if constexpr (N == 2) asm volatile("s_waitcnt vmcnt(2)" ::: "memory");
  else if constexpr (N == 3) asm volatile("s_waitcnt vmcnt(3)" ::: "memory");
  else if constexpr (N == 4) asm volatile("s_waitcnt vmcnt(4)" ::: "memory");
  else if constexpr (N == 5) asm volatile("s_waitcnt vmcnt(5)" ::: "memory");
  else if constexpr (N == 6) asm volatile("s_waitcnt vmcnt(6)" ::: "memory");
  else                       asm volatile("s_waitcnt vmcnt(8)" ::: "memory");
}

// ---------------- embedding + positional encoding ----------------
__global__ __launch_bounds__(256) void embed_k(const int* __restrict__ tok,
    const float* __restrict__ emb, float* __restrict__ x, u16* __restrict__ xb)
{
  const int l = blockIdx.x;
  const int d0 = threadIdx.x * 4;
  const int t = tok[l];
  const float lf = (float)l;
  float o[4]; u16 obv[4];
#pragma unroll
  for (int j = 0; j < 4; ++j) {
    int d = d0 + j;
    int p = d >> 1;
    float ang = lf * powf(10000.0f, -(float)(2 * p) / 1024.0f);
    float pe = (d & 1) ? cosf(ang) : sinf(ang);
    float val = 2.0f * emb[(size_t)t * DMODEL + d] * 55.42562584220407f + pe; // sqrt(3072)
    o[j] = val; obv[j] = f2b(val);
  }
  *reinterpret_cast<float4*>(x + (size_t)l * DMODEL + d0) = make_float4(o[0], o[1], o[2], o[3]);
  u16x4 vb = { obv[0], obv[1], obv[2], obv[3] };
  *reinterpret_cast<u16x4*>(xb + (size_t)l * DMODEL + d0) = vb;
}

// ---------------- residual-add (+P f32 partials, +opt bias) + LayerNorm ----------------
__global__ __launch_bounds__(256) void ln_k(const float* __restrict__ xin,
    const float* __restrict__ ypart, int P, const float* __restrict__ ybias,
    const float* __restrict__ s, const float* __restrict__ b,
    float* __restrict__ xout, u16* __restrict__ xbout)
{
  const int row = blockIdx.x, tid = threadIdx.x;
  const int d0 = tid * 4;
  float4 xv = *reinterpret_cast<const float4*>(xin + (size_t)row * DMODEL + d0);
  float t0 = xv.x, t1 = xv.y, t2 = xv.z, t3 = xv.w;
#pragma unroll 2
  for (int p = 0; p < P; ++p) {
    float4 yv = *reinterpret_cast<const float4*>(ypart + (size_t)p * (LSEQ * DMODEL) + (size_t)row * DMODEL + d0);
    t0 += yv.x; t1 += yv.y; t2 += yv.z; t3 += yv.w;
  }
  if (ybias) {
    float4 bb = *reinterpret_cast<const float4*>(ybias + d0);
    t0 += bb.x; t1 += bb.y; t2 += bb.z; t3 += bb.w;
  }
  float sum = t0 + t1 + t2 + t3;
  float sq  = t0 * t0 + t1 * t1 + t2 * t2 + t3 * t3;
#pragma unroll
  for (int d = 1; d < 64; d <<= 1) { sum += __shfl_xor(sum, d); sq += __shfl_xor(sq, d); }
  __shared__ float ssum[4], ssq[4];
  const int wid = tid >> 6;
  if ((tid & 63) == 0) { ssum[wid] = sum; ssq[wid] = sq; }
  __syncthreads();
  sum = ssum[0] + ssum[1] + ssum[2] + ssum[3];
  sq  = ssq[0] + ssq[1] + ssq[2] + ssq[3];
  const float mu = sum * (1.0f / 1024.0f);
  const float var = sq * (1.0f / 1024.0f) - mu * mu;
  const float rstd = rsqrtf(var + 1e-5f);
  float4 sv = *reinterpret_cast<const float4*>(s + d0);
  float4 bv = *reinterpret_cast<const float4*>(b + d0);
  float o0 = (t0 - mu) * rstd * sv.x + bv.x;
  float o1 = (t1 - mu) * rstd * sv.y + bv.y;
  float o2 = (t2 - mu) * rstd * sv.z + bv.z;
  float o3 = (t3 - mu) * rstd * sv.w + bv.w;
  *reinterpret_cast<float4*>(xout + (size_t)row * DMODEL + d0) = make_float4(o0, o1, o2, o3);
  u16x4 vb = { f2b(o0), f2b(o1), f2b(o2), f2b(o3) };
  *reinterpret_cast<u16x4*>(xbout + (size_t)row * DMODEL + d0) = vb;
}

// ---------------- residual-add (+P bf16 partial planes, +opt bias) + LayerNorm ----------------
__global__ __launch_bounds__(256) void lnb_k(const float* __restrict__ xin,
    const u16* __restrict__ ypart, int P, const float* __restrict__ ybias,
    const float* __restrict__ s, const float* __restrict__ b,
    float* __restrict__ xout, u16* __restrict__ xbout)
{
  const int row = blockIdx.x, tid = threadIdx.x;
  const int d0 = tid * 4;
  float4 xv = *reinterpret_cast<const float4*>(xin + (size_t)row * DMODEL + d0);
  float t0 = xv.x, t1 = xv.y, t2 = xv.z, t3 = xv.w;
#pragma unroll 4
  for (int p = 0; p < P; ++p) {
    u16x4 yv = *reinterpret_cast<const u16x4*>(ypart + (size_t)p * (LSEQ * DMODEL) + (size_t)row * DMODEL + d0);
    t0 += b2f(yv[0]); t1 += b2f(yv[1]); t2 += b2f(yv[2]); t3 += b2f(yv[3]);
  }
  if (ybias) {
    float4 bb = *reinterpret_cast<const float4*>(ybias + d0);
    t0 += bb.x; t1 += bb.y; t2 += bb.z; t3 += bb.w;
  }
  float sum = t0 + t1 + t2 + t3;
  float sq  = t0 * t0 + t1 * t1 + t2 * t2 + t3 * t3;
#pragma unroll
  for (int d = 1; d < 64; d <<= 1) { sum += __shfl_xor(sum, d); sq += __shfl_xor(sq, d); }
  __shared__ float ssum[4], ssq[4];
  const int wid = tid >> 6;
  if ((tid & 63) == 0) { ssum[wid] = sum; ssq[wid] = sq; }
  __syncthreads();
  sum = ssum[0] + ssum[1] + ssum[2] + ssum[3];
  sq  = ssq[0] + ssq[1] + ssq[2] + ssq[3];
  const float mu = sum * (1.0f / 1024.0f);
  const float var = sq * (1.0f / 1024.0f) - mu * mu;
  const float rstd = rsqrtf(var + 1e-5f);
  float4 sv = *reinterpret_cast<const float4*>(s + d0);
  float4 bv = *reinterpret_cast<const float4*>(b + d0);
  float o0 = (t0 - mu) * rstd * sv.x + bv.x;
  float o1 = (t1 - mu) * rstd * sv.y + bv.y;
  float o2 = (t2 - mu) * rstd * sv.z + bv.z;
  float o3 = (t3 - mu) * rstd * sv.w + bv.w;
  *reinterpret_cast<float4*>(xout + (size_t)row * DMODEL + d0) = make_float4(o0, o1, o2, o3);
  u16x4 vb = { f2b(o0), f2b(o1), f2b(o2), f2b(o3) };
  *reinterpret_cast<u16x4*>(xbout + (size_t)row * DMODEL + d0) = vb;
}

// ---------------- split-K reduce: FF1 (2 bf16 planes [L][4096] + bias, ReLU -> h1) ----------------
__global__ __launch_bounds__(256) void ffred_k(const u16* __restrict__ sp,
    const float* __restrict__ bias, u16* __restrict__ out)
{
  const size_t idx = ((size_t)blockIdx.x * 256 + threadIdx.x) * 8;
  const int c0 = (int)(idx % DFF);
  short8 a = *reinterpret_cast<const short8*>(sp + idx);
  short8 b = *reinterpret_cast<const short8*>(sp + (size_t)LSEQ * DFF + idx);
  short8 o;
#pragma unroll
  for (int j = 0; j < 8; ++j) {
    float val = b2f((u16)a[j]) + b2f((u16)b[j]) + bias[c0 + j];
    o[j] = (short)f2b(fmaxf(val, 0.0f));
  }
  *reinterpret_cast<short8*>(out + idx) = o;
}

// ---------------- transpose-convert: f32 in[R][C] -> bf16 out rows ----------------
__global__ __launch_bounds__(256) void tconv_k(const float* __restrict__ in, u16* __restrict__ out,
                                               int R, int C, int zper, int lstride, int obase, int zstride)
{
  __shared__ float t[64][65];
  const int rt = blockIdx.y * 64, ct = blockIdx.x * 64;
  const int z = blockIdx.z;
  in += (size_t)z * zstride;
  const int tr = threadIdx.x >> 4, tc = threadIdx.x & 15;
#pragma unroll
  for (int i = 0; i < 4; ++i) {
    int r = i * 16 + tr;
    float4 v = *reinterpret_cast<const float4*>(in + (size_t)(rt + r) * C + ct + tc * 4);
    t[r][tc * 4 + 0] = v.x; t[r][tc * 4 + 1] = v.y;
    t[r][tc * 4 + 2] = v.z; t[r][tc * 4 + 3] = v.w;
  }
  __syncthreads();
  const size_t orow0 = (size_t)(z / zper) * lstride + (size_t)(z % zper) * C + obase + ct;
#pragma unroll
  for (int i = 0; i < 4; ++i) {
    int c = i * 16 + tr;
    u16x4 o;
    o[0] = f2b(t[tc * 4 + 0][c]); o[1] = f2b(t[tc * 4 + 1][c]);
    o[2] = f2b(t[tc * 4 + 2][c]); o[3] = f2b(t[tc * 4 + 3][c]);
    *reinterpret_cast<u16x4*>(out + (orow0 + c) * R + rt + tc * 4) = o;
  }
}

// ---------------- elementwise convert f32 -> bf16 ----------------
__global__ __launch_bounds__(256) void ec_k(const float* __restrict__ in, u16* __restrict__ out)
{
  const size_t i = ((size_t)blockIdx.x * 256 + threadIdx.x) * 8;
  float4 a = *reinterpret_cast<const float4*>(in + i);
  float4 b = *reinterpret_cast<const float4*>(in + i + 4);
  short8 o;
  o[0] = f2b(a.x); o[1] = f2b(a.y); o[2] = f2b(a.z); o[3] = f2b(a.w);
  o[4] = f2b(b.x); o[5] = f2b(b.y); o[6] = f2b(b.z); o[7] = f2b(b.w);
  *reinterpret_cast<short8*>(out + i) = o;
}

// ---------------- bf16 MFMA GEMM, 3-stage counted-vmcnt pipeline ----------------
// C[M,N] = act(A[M,K] * Bt[N,K]^T + bias); grid: x = M tiles, y = N tiles, z = K split.
// Stride-aware bank swizzle: sw(row) = ((row*CPR)>>3) & (CPR-1).
// BSRC 0: A and B via global_load_lds into 3 slots, counted vmcnt (T4) + swizzle (T2).
// BSRC 1: f32 B^T reg-staged fallback (BK=32, BN=128), classic loop (slot 0 only).
// OUTMODE: 0 = f32 (KSPLIT>1: partial plane per z); 1 = bf16; 2 = QKV triple (q pre-scaled 1/32);
//          3 = bf16 partial plane per z (KSPLIT>1)
template<int BM, int BN, int BK, int BSRC, bool BIAS, bool RELU, int OUTMODE, int KSPLIT>
__global__ __launch_bounds__(256, 2) void gemm_bt(
    const u16* __restrict__ A, int lda,
    const void* __restrict__ Bp, int ldb,
    const float* __restrict__ bias,
    void* __restrict__ Cv, int ldc, int Ktot)
{
  constexpr int CPR = BK / 8;            // 16B chunks per row
  constexpr int SWM = CPR - 1;
  constexpr int LA = (BM * CPR) / 256;   // A loads/thread per K-tile
  constexpr int LB = (BN * CPR) / 256;   // B loads/thread per K-tile
  constexpr int LT = LA + LB;
  __shared__ u16 As[3][BM * BK];
  __shared__ u16 Bs[3][BN * BK];
  const int tid = threadIdx.x, lane = tid & 63, wid = tid >> 6;
  // chunked XCD swizzle on (x,y) (bijective: gx*gy is a multiple of 8 in all uses)
  const int nwg = gridDim.x * gridDim.y;
  const int flat = blockIdx.y * gridDim.x + blockIdx.x;
  const int qq = nwg >> 3;
  const int ni = (flat & 7) * qq + (flat >> 3);
  const int m0 = (ni % gridDim.x) * BM, n0 = (ni / gridDim.x) * BN;
  const int kbase = (KSPLIT > 1) ? blockIdx.z * (Ktot / KSPLIT) : 0;
  const int klen  = (KSPLIT > 1) ? (Ktot / KSPLIT) : Ktot;
  constexpr int FM = BM / 32, FN = BN / 32;
  constexpr int KS = BK / 32;
  const int wm = (wid >> 1) * (BM / 2), wn = (wid & 1) * (BN / 2);
  f32x4 acc[FM][FN] = {};

  if constexpr (BSRC == 0) {
    const u16* Bt = (const u16*)Bp;
    auto stage = [&](int slot, int k0) {
#pragma unroll
      for (int i = 0; i < LA; ++i) {
        int c = i * 256 + tid;
        int row = c / CPR, p0 = c % CPR;
        int part = p0 ^ (((row * CPR) >> 3) & SWM);
        gload16(A + (size_t)(m0 + row) * lda + k0 + part * 8,
                &As[slot][(i * 256 + wid * 64) * 8]);
      }
#pragma unroll
      for (int i = 0; i < LB; ++i) {
        int c = i * 256 + tid;
        int row = c / CPR, p0 = c % CPR;
        int part = p0 ^ (((row * CPR) >> 3) & SWM);
        gload16(Bt + (size_t)(n0 + row) * ldb + k0 + part * 8,
                &Bs[slot][(i * 256 + wid * 64) * 8]);
      }
    };

    const int NT = klen / BK;
    stage(0, kbase);
    stage(1, kbase + BK);
    waitvm<LT>();                        // tile 0 landed, tile 1 in flight
    __builtin_amdgcn_s_barrier();
    asm volatile("" ::: "memory");

    int cur = 0, stg = 2;
    for (int t = 0; t < NT; ++t) {
      const bool more = (t + 2 < NT);
      if (more) stage(stg, kbase + (t + 2) * BK);      // tile t+2 issued; stays in flight
      asm volatile("" ::: "memory");
      short8 a[KS][FM], b[KS][FN];
#pragma unroll
      for (int ks = 0; ks < KS; ++ks) {
#pragma unroll
        for (int fm = 0; fm < FM; ++fm) {
          int row = wm + fm * 16 + (lane & 15);
          int pidx = (ks * 4 + (lane >> 4)) ^ (((row * CPR) >> 3) & SWM);
          a[ks][fm] = *reinterpret_cast<const short8*>(&As[cur][row * BK + pidx * 8]);
        }
#pragma unroll
        for (int fn = 0; fn < FN; ++fn) {
          int row = wn + fn * 16 + (lane & 15);
          int pidx = (ks * 4 + (lane >> 4)) ^ (((row * CPR) >> 3) & SWM);
          b[ks][fn] = *reinterpret_cast<const short8*>(&Bs[cur][row * BK + pidx * 8]);
        }
      }
#pragma unroll
      for (int ks = 0; ks < KS; ++ks)
#pragma unroll
        for (int fm = 0; fm < FM; ++fm)
#pragma unroll
          for (int fn = 0; fn < FN; ++fn)
            acc[fm][fn] = mfma16(a[ks][fm], b[ks][fn], acc[fm][fn]);
      if (more) waitvm<LT>(); else waitvm<0>();
      __builtin_amdgcn_s_barrier();
      asm volatile("" ::: "memory");
      cur = (cur == 2) ? 0 : cur + 1;
      stg = (stg == 2) ? 0 : stg + 1;
    }
  } else {                       // f32 B^T fallback: BK=32, BN=128, slot 0 only
    const float* Bf = (const float*)Bp;
    for (int k0 = 0; k0 < Ktot; k0 += BK) {
#pragma unroll
      for (int i = 0; i < LA; ++i) {
        int c = i * 256 + tid;
        int row = c / CPR, part = c % CPR;
        gload16(A + (size_t)(m0 + row) * lda + k0 + part * 8,
                &As[0][(i * 256 + wid * 64) * 8]);
      }
      {
        int row = tid >> 1, kh = (tid & 1) * 16;
        const float* src = Bf + (size_t)(n0 + row) * ldb + k0 + kh;
        float4 v0 = *reinterpret_cast<const float4*>(src);
        float4 v1 = *reinterpret_cast<const float4*>(src + 4);
        float4 v2 = *reinterpret_cast<const float4*>(src + 8);
        float4 v3 = *reinterpret_cast<const float4*>(src + 12);
        short8 p0, p1;
        p0[0] = f2b(v0.x); p0[1] = f2b(v0.y); p0[2] = f2b(v0.z); p0[3] = f2b(v0.w);
        p0[4] = f2b(v1.x); p0[5] = f2b(v1.y); p0[6] = f2b(v1.z); p0[7] = f2b(v1.w);
        p1[0] = f2b(v2.x); p1[1] = f2b(v2.y); p1[2] = f2b(v2.z); p1[3] = f2b(v2.w);
        p1[4] = f2b(v3.x); p1[5] = f2b(v3.y); p1[6] = f2b(v3.z); p1[7] = f2b(v3.w);
        *reinterpret_cast<short8*>(&Bs[0][row * BK + kh])     = p0;
        *reinterpret_cast<short8*>(&Bs[0][row * BK + kh + 8]) = p1;
      }
      __syncthreads();
      short8 a[KS][FM], b[KS][FN];
#pragma unroll
      for (int ks = 0; ks < KS; ++ks) {
#pragma unroll
        for (int fm = 0; fm < FM; ++fm) {
          int row = wm + fm * 16 + (lane & 15);
          a[ks][fm] = *reinterpret_cast<const short8*>(&As[0][row * BK + (ks * 4 + (lane >> 4)) * 8]);
        }
#pragma unroll
        for (int fn = 0; fn < FN; ++fn) {
          int row = wn + fn * 16 + (lane & 15);
          b[ks][fn] = *reinterpret_cast<const short8*>(&Bs[0][row * BK + (ks * 4 + (lane >> 4)) * 8]);
        }
      }
#pragma unroll
      for (int ks = 0; ks < KS; ++ks)
#pragma unroll
        for (int fm = 0; fm < FM; ++fm)
#pragma unroll
          for (int fn = 0; fn < FN; ++fn)
            acc[fm][fn] = mfma16(a[ks][fm], b[ks][fn], acc[fm][fn]);
      __syncthreads();
    }
  }

  // ---- epilogue ----
  const size_t pbase = (KSPLIT > 1) ? (size_t)blockIdx.z * gridDim.x * BM * ldc : 0;
#pragma unroll
  for (int fm = 0; fm < FM; ++fm) {
#pragma unroll
    for (int fn = 0; fn < FN; ++fn) {
#pragma unroll
      for (int r = 0; r < 4; ++r) {
        int row = m0 + wm + fm * 16 + (lane >> 4) * 4 + r;
        int col = n0 + wn + fn * 16 + (lane & 15);
        float val = acc[fm][fn][r];
        if (BIAS) val += bias[col];
        if (RELU) val = fmaxf(val, 0.0f);
        if (OUTMODE == 0) {
          ((float*)Cv)[pbase + (size_t)row * ldc + col] = val;
        } else if (OUTMODE == 1) {
          ((u16*)Cv)[(size_t)row * ldc + col] = f2b(val);
        } else if (OUTMODE == 3) {
          ((u16*)Cv)[pbase + (size_t)row * ldc + col] = f2b(val);
        } else {
          int sel = col >> 10, cc = col & 1023;
          if (sel == 0) val *= 0.03125f;          // pre-scale q by 1/sqrt(d_model)
          ((u16*)Cv)[(size_t)sel * (LSEQ * DMODEL) + (size_t)row * DMODEL + cc] = f2b(val);
        }
      }
    }
  }
}

// ---------------- causal flash attention, KVBLK=64, async reg-staged K/V (T14) ----------------
// FUSE=1: q points at the QKV split-K bf16 partial planes sp [2][L][3072];
//         q/k/v combined (plane0+plane1, q scaled 1/32) at LDS-write time.
// FUSE=0: q/k/v separate [L][1024] bf16 buffers (q pre-scaled).
template<int FUSE>
__global__ __launch_bounds__(256) void attn_k(const u16* __restrict__ q,
    const u16* __restrict__ kmat, const u16* __restrict__ v, u16* __restrict__ o)
{
  __shared__ u16 Ks[64][72];
  __shared__ u16 Vt[64][72];
  __shared__ u16 Pl[4][16][72];
  const int tid = threadIdx.x, lane = tid & 63, wid = tid >> 6;
  const int h = blockIdx.y, qt = blockIdx.x;
  const int qw0 = qt * 64 + wid * 16;
  const int qrow = qw0 + (lane & 15);
  const size_t PLQ = (size_t)LSEQ * 3072;
  short8 aq0, aq1;
  if constexpr (FUSE) {
    const u16* qp = q + (size_t)qrow * 3072 + h * DHEAD + (lane >> 4) * 8;
    short8 a0 = *reinterpret_cast<const short8*>(qp);
    short8 b0 = *reinterpret_cast<const short8*>(qp + PLQ);
    short8 a1 = *reinterpret_cast<const short8*>(qp + 32);
    short8 b1 = *reinterpret_cast<const short8*>(qp + 32 + PLQ);
#pragma unroll
    for (int j = 0; j < 8; ++j) {
      aq0[j] = (short)f2b((b2f((u16)a0[j]) + b2f((u16)b0[j])) * 0.03125f);
      aq1[j] = (short)f2b((b2f((u16)a1[j]) + b2f((u16)b1[j])) * 0.03125f);
    }
  } else {
    aq0 = *reinterpret_cast<const short8*>(q + (size_t)qrow * DMODEL + h * DHEAD + (lane >> 4) * 8);
    aq1 = *reinterpret_cast<const short8*>(q + (size_t)qrow * DMODEL + h * DHEAD + 32 + (lane >> 4) * 8);
  }
  float m_run[4], l_run[4];
  f32x4 oacc[4] = {};
#pragma unroll
  for (int r = 0; r < 4; ++r) { m_run[r] = -1e30f; l_run[r] = 0.0f; }
  const int kvend = qt * 64 + 64;

  const int kvi = tid >> 2, c16 = (tid & 3) * 16;
  short8 kr0, kr1, vr0, vr1;
  short8 kr0b, kr1b, vr0b, vr1b;
  auto loadregs = [&](int kv0) {
    if constexpr (FUSE) {
      const u16* kp = q + (size_t)(kv0 + kvi) * 3072 + 1024 + h * DHEAD + c16;
      kr0  = *reinterpret_cast<const short8*>(kp);
      kr1  = *reinterpret_cast<const short8*>(kp + 8);
      kr0b = *reinterpret_cast<const short8*>(kp + PLQ);
      kr1b = *reinterpret_cast<const short8*>(kp + 8 + PLQ);
      const u16* vp = q + (size_t)(kv0 + kvi) * 3072 + 2048 + h * DHEAD + c16;
      vr0  = *reinterpret_cast<const short8*>(vp);
      vr1  = *reinterpret_cast<const short8*>(vp + 8);
      vr0b = *reinterpret_cast<const short8*>(vp + PLQ);
      vr1b = *reinterpret_cast<const short8*>(vp + 8 + PLQ);
    } else {
      const u16* kp = kmat + (size_t)(kv0 + kvi) * DMODEL + h * DHEAD + c16;
      kr0 = *reinterpret_cast<const short8*>(kp);
      kr1 = *reinterpret_cast<const short8*>(kp + 8);
      const u16* vp = v + (size_t)(kv0 + kvi) * DMODEL + h * DHEAD + c16;
      vr0 = *reinterpret_cast<const short8*>(vp);
      vr1 = *reinterpret_cast<const short8*>(vp + 8);
    }
  };
  loadregs(0);

  for (int kv0 = 0; kv0 < kvend; kv0 += 64) {
    __syncthreads();
    if constexpr (FUSE) {
      short8 ko0, ko1;
#pragma unroll
      for (int j = 0; j < 8; ++j) {
        ko0[j] = (short)f2b(b2f((u16)kr0[j]) + b2f((u16)kr0b[j]));
        ko1[j] = (short)f2b(b2f((u16)kr1[j]) + b2f((u16)kr1b[j]));
      }
      *reinterpret_cast<short8*>(&Ks[kvi][c16])     = ko0;
      *reinterpret_cast<short8*>(&Ks[kvi][c16 + 8]) = ko1;
#pragma unroll
      for (int j = 0; j < 8; ++j) {
        Vt[c16 + j][kvi]     = f2b(b2f((u16)vr0[j]) + b2f((u16)vr0b[j]));
        Vt[c16 + 8 + j][kvi] = f2b(b2f((u16)vr1[j]) + b2f((u16)vr1b[j]));
      }
    } else {
      *reinterpret_cast<short8*>(&Ks[kvi][c16])     = kr0;
      *reinterpret_cast<short8*>(&Ks[kvi][c16 + 8]) = kr1;
#pragma unroll
      for (int j = 0; j < 8; ++j) { Vt[c16 + j][kvi] = (u16)vr0[j]; Vt[c16 + 8 + j][kvi] = (u16)vr1[j]; }
    }
    __syncthreads();
    if (kv0 + 64 < kvend) loadregs(kv0 + 64);

    float sm[4][4];
#pragma unroll
    for (int t2 = 0; t2 < 4; ++t2) {
      short8 bk0 = *reinterpret_cast<const short8*>(&Ks[t2 * 16 + (lane & 15)][(lane >> 4) * 8]);
      short8 bk1 = *reinterpret_cast<const short8*>(&Ks[t2 * 16 + (lane & 15)][32 + (lane >> 4) * 8]);
      f32x4 s4 = {};
      s4 = mfma16(aq0, bk0, s4);
      s4 = mfma16(aq1, bk1, s4);
#pragma unroll
      for (int r = 0; r < 4; ++r) {
        int rowg = qw0 + (lane >> 4) * 4 + r;
        int colg = kv0 + t2 * 16 + (lane & 15);
        sm[t2][r] = (colg <= rowg) ? s4[r] : -1e30f;
      }
    }
    float alpha[4], p[4][4];
#pragma unroll
    for (int r = 0; r < 4; ++r) {
      float mx = fmaxf(fmaxf(sm[0][r], sm[1][r]), fmaxf(sm[2][r], sm[3][r]));
#pragma unroll
      for (int d = 1; d < 16; d <<= 1) mx = fmaxf(mx, __shfl_xor(mx, d));
      float mn = fmaxf(m_run[r], mx);
      alpha[r] = __expf(m_run[r] - mn);
      float ps = 0.0f;
#pragma unroll
      for (int t2 = 0; t2 < 4; ++t2) { p[t2][r] = __expf(sm[t2][r] - mn); ps += p[t2][r]; }
#pragma unroll
      for (int d = 1; d < 16; d <<= 1) ps += __shfl_xor(ps, d);
      l_run[r] = l_run[r] * alpha[r] + ps;
      m_run[r] = mn;
    }
#pragma unroll
    for (int fn = 0; fn < 4; ++fn) {
      f32x4 t = oacc[fn];
      t[0] *= alpha[0]; t[1] *= alpha[1]; t[2] *= alpha[2]; t[3] *= alpha[3];
      oacc[fn] = t;
    }
#pragma unroll
    for (int r = 0; r < 4; ++r) {
      int rit = (lane >> 4) * 4 + r;
#pragma unroll
      for (int t2 = 0; t2 < 4; ++t2)
        Pl[wid][rit][t2 * 16 + (lane & 15)] = f2b(p[t2][r]);
    }
    short8 pa0 = *reinterpret_cast<const short8*>(&Pl[wid][lane & 15][(lane >> 4) * 8]);
    short8 pa1 = *reinterpret_cast<const short8*>(&Pl[wid][lane & 15][32 + (lane >> 4) * 8]);
#pragma unroll
    for (int fn = 0; fn < 4; ++fn) {
      short8 bv0 = *reinterpret_cast<const short8*>(&Vt[fn * 16 + (lane & 15)][(lane >> 4) * 8]);
      short8 bv1 = *reinterpret_cast<const short8*>(&Vt[fn * 16 + (lane & 15)][32 + (lane >> 4) * 8]);
      oacc[fn] = mfma16(pa0, bv0, oacc[fn]);
      oacc[fn] = mfma16(pa1, bv1, oacc[fn]);
    }
  }
#pragma unroll
  for (int fn = 0; fn < 4; ++fn) {
#pragma unroll
    for (int r = 0; r < 4; ++r) {
      int row = qw0 + (lane >> 4) * 4 + r;
      float val = oacc[fn][r] / l_run[r];
      o[(size_t)row * DMODEL + h * DHEAD + fn * 16 + (lane & 15)] = f2b(val);
    }
  }
}

// ---------------- launch ----------------
extern "C" void kernel_launch(void* const* d_in, const int* in_sizes, int n_in,
                              void* d_out, int out_size, void* d_ws, size_t ws_size,
                              hipStream_t stream) {
  (void)in_sizes; (void)n_in; (void)out_size;
  const int*   tok    = (const int*)d_in[0];
  const float* emb    = (const float*)d_in[1];
  const float* finalb = (const float*)d_in[2];
  const float* Wq     = (const float*)d_in[3];
  const float* Wk     = (const float*)d_in[4];
  const float* Wv     = (const float*)d_in[5];
  const float* Wo     = (const float*)d_in[6];
  const float* ln1s   = (const float*)d_in[7];
  const float* ln1b   = (const float*)d_in[8];
  const float* W1     = (const float*)d_in[9];
  const float* b1     = (const float*)d_in[10];
  const float* W2     = (const float*)d_in[11];
  const float* b2     = (const float*)d_in[12];
  const float* ln2s   = (const float*)d_in[13];
  const float* ln2b   = (const float*)d_in[14];
  float* out = (float*)d_out;

  // workspace: activations
  float* x   = (float*)d_ws;                       // 4 MiB
  float* y   = x + LSEQ * DMODEL;                  // 4 MiB (scratch)
  u16* xb    = (u16*)(y + LSEQ * DMODEL);
  u16* qb    = xb + LSEQ * DMODEL;                 // fallback q/k/v
  u16* kb    = qb + LSEQ * DMODEL;
  u16* vb    = kb + LSEQ * DMODEL;
  u16* ob    = vb + LSEQ * DMODEL;
  u16* h1    = ob + LSEQ * DMODEL;                 // 8 MiB
  u16* wbase = h1 + LSEQ * DFF;
  float* woPart = (float*)h1;   // 2 f32 planes (8 MiB) — h1 free during Wo GEMM

  const size_t eQKV = (size_t)3 * DMODEL * DMODEL;
  const size_t eWO  = (size_t)DMODEL * DMODEL;
  const size_t eW1  = (size_t)DFF * DMODEL;
  const size_t eW2  = (size_t)DMODEL * DFF;
  const size_t perL = eQKV + eWO + eW1 + eW2;
  const size_t eEMB = (size_t)NVOCAB * DMODEL;
  const size_t eSP  = (size_t)2 * LSEQ * DFF;        // split-K bf16 partials (16 MiB)
  const size_t actE = (size_t)(wbase - (u16*)d_ws);
  const size_t bigNeed = (actE + NLAYER * perL + eEMB + eSP) * 2;
  const size_t midNeed = (actE + perL + eEMB) * 2;
  const int mode = ws_size >= bigNeed ? 2 : (ws_size >= midNeed ? 1 : 0);
  const int WL = (mode == 2) ? NLAYER : 1;

  u16* qkvT = wbase;
  u16* woT  = qkvT + WL * eQKV;
  u16* w1T  = woT  + WL * eWO;
  u16* w2T  = w1T  + WL * eW1;
  u16* embT = w2T  + WL * eW2;
  u16* sp   = embT + eEMB;                           // bf16 split-K partial planes

  if (mode == 2) {
    tconv_k<<<dim3(1, 16, 192), 256, 0, stream>>>(Wq, qkvT, DMODEL, DHEAD, 16, 3 * DMODEL, 0,    DMODEL * DHEAD);
    tconv_k<<<dim3(1, 16, 192), 256, 0, stream>>>(Wk, qkvT, DMODEL, DHEAD, 16, 3 * DMODEL, 1024, DMODEL * DHEAD);
    tconv_k<<<dim3(1, 16, 192), 256, 0, stream>>>(Wv, qkvT, DMODEL, DHEAD, 16, 3 * DMODEL, 2048, DMODEL * DHEAD);
    tconv_k<<<dim3(16, 16, 12), 256, 0, stream>>>(Wo, woT, DMODEL, DMODEL, 1, DMODEL, 0, DMODEL * DMODEL);
    tconv_k<<<dim3(64, 16, 12), 256, 0, stream>>>(W1, w1T, DMODEL, DFF, 1, DFF, 0, DMODEL * DFF);
    tconv_k<<<dim3(16, 64, 12), 256, 0, stream>>>(W2, w2T, DFF, DMODEL, 1, DMODEL, 0, DFF * DMODEL);
    ec_k<<<(NVOCAB * DMODEL) / 2048, 256, 0, stream>>>(emb, embT);
  } else if (mode == 1) {
    ec_k<<<(NVOCAB * DMODEL) / 2048, 256, 0, stream>>>(emb, embT);
  }

  embed_k<<<LSEQ, 256, 0, stream>>>(tok, emb, x, xb);

  for (int l = 0; l < NLAYER; ++l) {
    const float* wq  = Wq + (size_t)l * NHEAD * DMODEL * DHEAD;
    const float* wk  = Wk + (size_t)l * NHEAD * DMODEL * DHEAD;
    const float* wv  = Wv + (size_t)l * NHEAD * DMODEL * DHEAD;
    const float* wo  = Wo + (size_t)l * DMODEL * DMODEL;
    const float* w1  = W1 + (size_t)l * DMODEL * DFF;
    const float* b1l = b1 + (size_t)l * DFF;
    const float* w2  = W2 + (size_t)l * DFF * DMODEL;
    const float* b2l = b2 + (size_t)l * DMODEL;
    u16* qkvTl = qkvT + (mode == 2 ? (size_t)l * eQKV : 0);
    u16* woTl  = woT  + (mode == 2 ? (size_t)l * eWO  : 0);
    u16* w1Tl  = w1T  + (mode == 2 ? (size_t)l * eW1  : 0);
    u16* w2Tl  = w2T  + (mode == 2 ? (size_t)l * eW2  : 0);

    if (mode < 2) {
      tconv_k<<<dim3(1, 16, 16), 256, 0, stream>>>(wq, qkvTl, DMODEL, DHEAD, 16, 0, 0,    DMODEL * DHEAD);
      tconv_k<<<dim3(1, 16, 16), 256, 0, stream>>>(wk, qkvTl, DMODEL, DHEAD, 16, 0, 1024, DMODEL * DHEAD);
      tconv_k<<<dim3(1, 16, 16), 256, 0, stream>>>(wv, qkvTl, DMODEL, DHEAD, 16, 0, 2048, DMODEL * DHEAD);
      tconv_k<<<dim3(16, 16, 1), 256, 0, stream>>>(wo, woTl, DMODEL, DMODEL, 1, 0, 0, 0);
      tconv_k<<<dim3(64, 16, 1), 256, 0, stream>>>(w1, w1Tl, DMODEL, DFF, 1, 0, 0, 0);
      tconv_k<<<dim3(16, 64, 1), 256, 0, stream>>>(w2, w2Tl, DFF, DMODEL, 1, 0, 0, 0);
    }

    if (mode == 2) {
      // QKV: 128x128 BK32, split-K 2 (grid 8x24x2 = 384 blocks), bf16 partials -> sp
      gemm_bt<128, 128, 32, 0, false, false, 3, 2><<<dim3(8, 24, 2), 256, 0, stream>>>(
          xb, DMODEL, qkvTl, DMODEL, nullptr, sp, 3 * DMODEL, DMODEL);
      // attention reads the partial planes directly (fused reduce + q-scale)
      attn_k<1><<<dim3(16, 16), 256, 0, stream>>>(sp, nullptr, nullptr, ob);
    } else {
      gemm_bt<64, 64, 64, 0, false, false, 2, 1><<<dim3(16, 48), 256, 0, stream>>>(
          xb, DMODEL, qkvTl, DMODEL, nullptr, qb, DMODEL, DMODEL);
      attn_k<0><<<dim3(16, 16), 256, 0, stream>>>(qb, kb, vb, ob);
    }
    // Wo: 64x64 BK64, split-K 2 (grid 16x16x2 = 512 blocks), f32 partials -> h1 region
    gemm_bt<64, 64, 64, 0, false, false, 0, 2><<<dim3(16, 16, 2), 256, 0, stream>>>(
        ob, DMODEL, woTl, DMODEL, nullptr, woPart, DMODEL, DMODEL);
    ln_k<<<LSEQ, 256, 0, stream>>>(x, woPart, 2, nullptr,
        ln1s + (size_t)l * DMODEL, ln1b + (size_t)l * DMODEL, x, xb);
    if (mode == 2) {
      // FF1: 128x128 BK32, split-K 2 (grid 8x32x2 = 512 blocks), bf16 partials -> sp
      gemm_bt<128, 128, 32, 0, false, false, 3, 2><<<dim3(8, 32, 2), 256, 0, stream>>>(
          xb, DMODEL, w1Tl, DMODEL, nullptr, sp, DFF, DMODEL);
      ffred_k<<<(LSEQ * DFF) / 2048, 256, 0, stream>>>(sp, b1l, h1);
      // FF2: 128x128 BK32, split-K 8 (grid 8x8x8 = 512 blocks), bf16 partials -> sp
      gemm_bt<128, 128, 32, 0, false, false, 3, 8><<<dim3(8, 8, 8), 256, 0, stream>>>(
          h1, DFF, w2Tl, DFF, nullptr, sp, DMODEL, DFF);
      lnb_k<<<LSEQ, 256, 0, stream>>>(x, sp, 8, b2l,
          ln2s + (size_t)l * DMODEL, ln2b + (size_t)l * DMODEL, x, xb);
    } else {
      gemm_bt<64, 64, 64, 0, true, true, 1, 1><<<dim3(16, 64), 256, 0, stream>>>(
          xb, DMODEL, w1Tl, DMODEL, b1l, h1, DFF, DMODEL);
      gemm_bt<64, 64, 64, 0, false, false, 0, 2><<<dim3(16, 16, 2), 256, 0, stream>>>(
          h1, DFF, w2Tl, DFF, nullptr, (float*)qb, DMODEL, DFF);
      ln_k<<<LSEQ, 256, 0, stream>>>(x, (float*)qb, 2, b2l,
          ln2s + (size_t)l * DMODEL, ln2b + (size_t)l * DMODEL, x, xb);
    }
  }

  // logits = x @ emb^T + final_b
  // BM=256 (wave tile 128x64): 42.7 FLOP per LDS byte vs 32 at BM=128 — raises the
  // ds_read-throughput ceiling. 72KB LDS -> 2 blocks/CU; grid 4x250 = 1000 blocks.
  if (mode >= 1) {
    gemm_bt<256, 128, 32, 0, true, false, 0, 1><<<dim3(4, 250), 256, 0, stream>>>(
        xb, DMODEL, embT, DMODEL, finalb, out, NVOCAB, DMODEL);
  } else {
    gemm_bt<128, 128, 32, 1, true, false, 0, 1><<<dim3(8, 250), 256, 0, stream>>>(
        xb, DMODEL, emb, DMODEL, finalb, out, NVOCAB, DMODEL);
  }
}

// Round 13
// 1764.986 us; speedup vs baseline: 1.0847x; 1.0049x over previous
//
#include <hip/hip_runtime.h>

typedef unsigned short u16;
typedef __attribute__((ext_vector_type(8))) short short8;
typedef __attribute__((ext_vector_type(4))) float f32x4;
typedef __attribute__((ext_vector_type(4))) u16 u16x4;

#define LSEQ   1024
#define DMODEL 1024
#define NHEAD  16
#define DHEAD  64
#define DFF    4096
#define NLAYER 12
#define NVOCAB 32000

__device__ __forceinline__ u16 f2b(float f) {
  union { float f; unsigned u; } x; x.f = f;
  unsigned r = x.u + 0x7fffu + ((x.u >> 16) & 1u);   // RNE
  return (u16)(r >> 16);
}
__device__ __forceinline__ float b2f(u16 u) {
  union { unsigned u; float f; } x; x.u = ((unsigned)u) << 16; return x.f;
}

__device__ __forceinline__ f32x4 mfma16(short8 a, short8 b, f32x4 c) {
  return __builtin_amdgcn_mfma_f32_16x16x32_bf16(a, b, c, 0, 0, 0);
}

// async global->LDS, 16B per lane. LDS dest = wave-uniform base + lane*16.
__device__ __forceinline__ void gload16(const u16* g, u16* l) {
  __builtin_amdgcn_global_load_lds(
      (const __attribute__((address_space(1))) void*)g,
      (__attribute__((address_space(3))) void*)l, 16, 0, 0);
}

template<int N> __device__ __forceinline__ void waitvm() {
  if constexpr (N <= 0)      asm volatile("s_waitcnt vmcnt(0)" ::: "memory");
  else if constexpr (N == 1) asm volatile("s_waitcnt vmcnt(1)" ::: "memory");
  else if constexpr (N == 2) asm volatile("s_waitcnt vmcnt(2)" ::: "memory");
  else if constexpr (N == 3) asm volatile("s_waitcnt vmcnt(3)" ::: "memory");
  else if constexpr (N == 4) asm volatile("s_waitcnt vmcnt(4)" ::: "memory");
  else if constexpr (N == 5) asm volatile("s_waitcnt vmcnt(5)" ::: "memory");
  else if constexpr (N == 6) asm volatile("s_waitcnt vmcnt(6)" ::: "memory");
  else                       asm volatile("s_waitcnt vmcnt(8)" ::: "memory");
}

// ---------------- embedding + positional encoding ----------------
__global__ __launch_bounds__(256) void embed_k(const int* __restrict__ tok,
    const float* __restrict__ emb, float* __restrict__ x, u16* __restrict__ xb)
{
  const int l = blockIdx.x;
  const int d0 = threadIdx.x * 4;
  const int t = tok[l];
  const float lf = (float)l;
  float o[4]; u16 obv[4];
#pragma unroll
  for (int j = 0; j < 4; ++j) {
    int d = d0 + j;
    int p = d >> 1;
    float ang = lf * powf(10000.0f, -(float)(2 * p) / 1024.0f);
    float pe = (d & 1) ? cosf(ang) : sinf(ang);
    float val = 2.0f * emb[(size_t)t * DMODEL + d] * 55.42562584220407f + pe; // sqrt(3072)
    o[j] = val; obv[j] = f2b(val);
  }
  *reinterpret_cast<float4*>(x + (size_t)l * DMODEL + d0) = make_float4(o[0], o[1], o[2], o[3]);
  u16x4 vb = { obv[0], obv[1], obv[2], obv[3] };
  *reinterpret_cast<u16x4*>(xb + (size_t)l * DMODEL + d0) = vb;
}

// ---------------- residual-add (+P f32 partials, +opt bias) + LayerNorm ----------------
__global__ __launch_bounds__(256) void ln_k(const float* __restrict__ xin,
    const float* __restrict__ ypart, int P, const float* __restrict__ ybias,
    const float* __restrict__ s, const float* __restrict__ b,
    float* __restrict__ xout, u16* __restrict__ xbout)
{
  const int row = blockIdx.x, tid = threadIdx.x;
  const int d0 = tid * 4;
  float4 xv = *reinterpret_cast<const float4*>(xin + (size_t)row * DMODEL + d0);
  float t0 = xv.x, t1 = xv.y, t2 = xv.z, t3 = xv.w;
#pragma unroll 2
  for (int p = 0; p < P; ++p) {
    float4 yv = *reinterpret_cast<const float4*>(ypart + (size_t)p * (LSEQ * DMODEL) + (size_t)row * DMODEL + d0);
    t0 += yv.x; t1 += yv.y; t2 += yv.z; t3 += yv.w;
  }
  if (ybias) {
    float4 bb = *reinterpret_cast<const float4*>(ybias + d0);
    t0 += bb.x; t1 += bb.y; t2 += bb.z; t3 += bb.w;
  }
  float sum = t0 + t1 + t2 + t3;
  float sq  = t0 * t0 + t1 * t1 + t2 * t2 + t3 * t3;
#pragma unroll
  for (int d = 1; d < 64; d <<= 1) { sum += __shfl_xor(sum, d); sq += __shfl_xor(sq, d); }
  __shared__ float ssum[4], ssq[4];
  const int wid = tid >> 6;
  if ((tid & 63) == 0) { ssum[wid] = sum; ssq[wid] = sq; }
  __syncthreads();
  sum = ssum[0] + ssum[1] + ssum[2] + ssum[3];
  sq  = ssq[0] + ssq[1] + ssq[2] + ssq[3];
  const float mu = sum * (1.0f / 1024.0f);
  const float var = sq * (1.0f / 1024.0f) - mu * mu;
  const float rstd = rsqrtf(var + 1e-5f);
  float4 sv = *reinterpret_cast<const float4*>(s + d0);
  float4 bv = *reinterpret_cast<const float4*>(b + d0);
  float o0 = (t0 - mu) * rstd * sv.x + bv.x;
  float o1 = (t1 - mu) * rstd * sv.y + bv.y;
  float o2 = (t2 - mu) * rstd * sv.z + bv.z;
  float o3 = (t3 - mu) * rstd * sv.w + bv.w;
  *reinterpret_cast<float4*>(xout + (size_t)row * DMODEL + d0) = make_float4(o0, o1, o2, o3);
  u16x4 vb = { f2b(o0), f2b(o1), f2b(o2), f2b(o3) };
  *reinterpret_cast<u16x4*>(xbout + (size_t)row * DMODEL + d0) = vb;
}

// ---------------- residual-add (+P bf16 partial planes, +opt bias) + LayerNorm ----------------
__global__ __launch_bounds__(256) void lnb_k(const float* __restrict__ xin,
    const u16* __restrict__ ypart, int P, const float* __restrict__ ybias,
    const float* __restrict__ s, const float* __restrict__ b,
    float* __restrict__ xout, u16* __restrict__ xbout)
{
  const int row = blockIdx.x, tid = threadIdx.x;
  const int d0 = tid * 4;
  float4 xv = *reinterpret_cast<const float4*>(xin + (size_t)row * DMODEL + d0);
  float t0 = xv.x, t1 = xv.y, t2 = xv.z, t3 = xv.w;
#pragma unroll 4
  for (int p = 0; p < P; ++p) {
    u16x4 yv = *reinterpret_cast<const u16x4*>(ypart + (size_t)p * (LSEQ * DMODEL) + (size_t)row * DMODEL + d0);
    t0 += b2f(yv[0]); t1 += b2f(yv[1]); t2 += b2f(yv[2]); t3 += b2f(yv[3]);
  }
  if (ybias) {
    float4 bb = *reinterpret_cast<const float4*>(ybias + d0);
    t0 += bb.x; t1 += bb.y; t2 += bb.z; t3 += bb.w;
  }
  float sum = t0 + t1 + t2 + t3;
  float sq  = t0 * t0 + t1 * t1 + t2 * t2 + t3 * t3;
#pragma unroll
  for (int d = 1; d < 64; d <<= 1) { sum += __shfl_xor(sum, d); sq += __shfl_xor(sq, d); }
  __shared__ float ssum[4], ssq[4];
  const int wid = tid >> 6;
  if ((tid & 63) == 0) { ssum[wid] = sum; ssq[wid] = sq; }
  __syncthreads();
  sum = ssum[0] + ssum[1] + ssum[2] + ssum[3];
  sq  = ssq[0] + ssq[1] + ssq[2] + ssq[3];
  const float mu = sum * (1.0f / 1024.0f);
  const float var = sq * (1.0f / 1024.0f) - mu * mu;
  const float rstd = rsqrtf(var + 1e-5f);
  float4 sv = *reinterpret_cast<const float4*>(s + d0);
  float4 bv = *reinterpret_cast<const float4*>(b + d0);
  float o0 = (t0 - mu) * rstd * sv.x + bv.x;
  float o1 = (t1 - mu) * rstd * sv.y + bv.y;
  float o2 = (t2 - mu) * rstd * sv.z + bv.z;
  float o3 = (t3 - mu) * rstd * sv.w + bv.w;
  *reinterpret_cast<float4*>(xout + (size_t)row * DMODEL + d0) = make_float4(o0, o1, o2, o3);
  u16x4 vb = { f2b(o0), f2b(o1), f2b(o2), f2b(o3) };
  *reinterpret_cast<u16x4*>(xbout + (size_t)row * DMODEL + d0) = vb;
}

// ---------------- split-K reduce: FF1 (2 bf16 planes [L][4096] + bias, ReLU -> h1) ----------------
__global__ __launch_bounds__(256) void ffred_k(const u16* __restrict__ sp,
    const float* __restrict__ bias, u16* __restrict__ out)
{
  const size_t idx = ((size_t)blockIdx.x * 256 + threadIdx.x) * 8;
  const int c0 = (int)(idx % DFF);
  short8 a = *reinterpret_cast<const short8*>(sp + idx);
  short8 b = *reinterpret_cast<const short8*>(sp + (size_t)LSEQ * DFF + idx);
  short8 o;
#pragma unroll
  for (int j = 0; j < 8; ++j) {
    float val = b2f((u16)a[j]) + b2f((u16)b[j]) + bias[c0 + j];
    o[j] = (short)f2b(fmaxf(val, 0.0f));
  }
  *reinterpret_cast<short8*>(out + idx) = o;
}

// ---------------- transpose-convert: f32 in[R][C] -> bf16 out rows ----------------
__global__ __launch_bounds__(256) void tconv_k(const float* __restrict__ in, u16* __restrict__ out,
                                               int R, int C, int zper, int lstride, int obase, int zstride)
{
  __shared__ float t[64][65];
  const int rt = blockIdx.y * 64, ct = blockIdx.x * 64;
  const int z = blockIdx.z;
  in += (size_t)z * zstride;
  const int tr = threadIdx.x >> 4, tc = threadIdx.x & 15;
#pragma unroll
  for (int i = 0; i < 4; ++i) {
    int r = i * 16 + tr;
    float4 v = *reinterpret_cast<const float4*>(in + (size_t)(rt + r) * C + ct + tc * 4);
    t[r][tc * 4 + 0] = v.x; t[r][tc * 4 + 1] = v.y;
    t[r][tc * 4 + 2] = v.z; t[r][tc * 4 + 3] = v.w;
  }
  __syncthreads();
  const size_t orow0 = (size_t)(z / zper) * lstride + (size_t)(z % zper) * C + obase + ct;
#pragma unroll
  for (int i = 0; i < 4; ++i) {
    int c = i * 16 + tr;
    u16x4 o;
    o[0] = f2b(t[tc * 4 + 0][c]); o[1] = f2b(t[tc * 4 + 1][c]);
    o[2] = f2b(t[tc * 4 + 2][c]); o[3] = f2b(t[tc * 4 + 3][c]);
    *reinterpret_cast<u16x4*>(out + (orow0 + c) * R + rt + tc * 4) = o;
  }
}

// ---------------- elementwise convert f32 -> bf16 ----------------
__global__ __launch_bounds__(256) void ec_k(const float* __restrict__ in, u16* __restrict__ out)
{
  const size_t i = ((size_t)blockIdx.x * 256 + threadIdx.x) * 8;
  float4 a = *reinterpret_cast<const float4*>(in + i);
  float4 b = *reinterpret_cast<const float4*>(in + i + 4);
  short8 o;
  o[0] = f2b(a.x); o[1] = f2b(a.y); o[2] = f2b(a.z); o[3] = f2b(a.w);
  o[4] = f2b(b.x); o[5] = f2b(b.y); o[6] = f2b(b.z); o[7] = f2b(b.w);
  *reinterpret_cast<short8*>(out + i) = o;
}

// ---------------- bf16 MFMA GEMM, 3-stage counted-vmcnt pipeline ----------------
// C[M,N] = act(A[M,K] * Bt[N,K]^T + bias); grid: x = M tiles, y = N tiles, z = K split.
// Stride-aware bank swizzle: sw(row) = ((row*CPR)>>3) & (CPR-1).
// BSRC 0: A and B via global_load_lds into 3 slots, counted vmcnt (T4) + swizzle (T2)
//         + s_setprio around the MFMA cluster (T5).
// BSRC 1: f32 B^T reg-staged fallback (BK=32, BN=128), classic loop (slot 0 only).
// OUTMODE: 0 = f32 (KSPLIT>1: partial plane per z); 1 = bf16; 2 = QKV triple (q pre-scaled 1/32);
//          3 = bf16 partial plane per z (KSPLIT>1)
template<int BM, int BN, int BK, int BSRC, bool BIAS, bool RELU, int OUTMODE, int KSPLIT>
__global__ __launch_bounds__(256, 2) void gemm_bt(
    const u16* __restrict__ A, int lda,
    const void* __restrict__ Bp, int ldb,
    const float* __restrict__ bias,
    void* __restrict__ Cv, int ldc, int Ktot)
{
  constexpr int CPR = BK / 8;            // 16B chunks per row
  constexpr int SWM = CPR - 1;
  constexpr int LA = (BM * CPR) / 256;   // A loads/thread per K-tile
  constexpr int LB = (BN * CPR) / 256;   // B loads/thread per K-tile
  constexpr int LT = LA + LB;
  __shared__ u16 As[3][BM * BK];
  __shared__ u16 Bs[3][BN * BK];
  const int tid = threadIdx.x, lane = tid & 63, wid = tid >> 6;
  // chunked XCD swizzle on (x,y) (bijective: gx*gy is a multiple of 8 in all uses)
  const int nwg = gridDim.x * gridDim.y;
  const int flat = blockIdx.y * gridDim.x + blockIdx.x;
  const int qq = nwg >> 3;
  const int ni = (flat & 7) * qq + (flat >> 3);
  const int m0 = (ni % gridDim.x) * BM, n0 = (ni / gridDim.x) * BN;
  const int kbase = (KSPLIT > 1) ? blockIdx.z * (Ktot / KSPLIT) : 0;
  const int klen  = (KSPLIT > 1) ? (Ktot / KSPLIT) : Ktot;
  constexpr int FM = BM / 32, FN = BN / 32;
  constexpr int KS = BK / 32;
  const int wm = (wid >> 1) * (BM / 2), wn = (wid & 1) * (BN / 2);
  f32x4 acc[FM][FN] = {};

  if constexpr (BSRC == 0) {
    const u16* Bt = (const u16*)Bp;
    auto stage = [&](int slot, int k0) {
#pragma unroll
      for (int i = 0; i < LA; ++i) {
        int c = i * 256 + tid;
        int row = c / CPR, p0 = c % CPR;
        int part = p0 ^ (((row * CPR) >> 3) & SWM);
        gload16(A + (size_t)(m0 + row) * lda + k0 + part * 8,
                &As[slot][(i * 256 + wid * 64) * 8]);
      }
#pragma unroll
      for (int i = 0; i < LB; ++i) {
        int c = i * 256 + tid;
        int row = c / CPR, p0 = c % CPR;
        int part = p0 ^ (((row * CPR) >> 3) & SWM);
        gload16(Bt + (size_t)(n0 + row) * ldb + k0 + part * 8,
                &Bs[slot][(i * 256 + wid * 64) * 8]);
      }
    };

    const int NT = klen / BK;
    stage(0, kbase);
    stage(1, kbase + BK);
    waitvm<LT>();                        // tile 0 landed, tile 1 in flight
    __builtin_amdgcn_s_barrier();
    asm volatile("" ::: "memory");

    int cur = 0, stg = 2;
    for (int t = 0; t < NT; ++t) {
      const bool more = (t + 2 < NT);
      if (more) stage(stg, kbase + (t + 2) * BK);      // tile t+2 issued; stays in flight
      asm volatile("" ::: "memory");
      short8 a[KS][FM], b[KS][FN];
#pragma unroll
      for (int ks = 0; ks < KS; ++ks) {
#pragma unroll
        for (int fm = 0; fm < FM; ++fm) {
          int row = wm + fm * 16 + (lane & 15);
          int pidx = (ks * 4 + (lane >> 4)) ^ (((row * CPR) >> 3) & SWM);
          a[ks][fm] = *reinterpret_cast<const short8*>(&As[cur][row * BK + pidx * 8]);
        }
#pragma unroll
        for (int fn = 0; fn < FN; ++fn) {
          int row = wn + fn * 16 + (lane & 15);
          int pidx = (ks * 4 + (lane >> 4)) ^ (((row * CPR) >> 3) & SWM);
          b[ks][fn] = *reinterpret_cast<const short8*>(&Bs[cur][row * BK + pidx * 8]);
        }
      }
      __builtin_amdgcn_s_setprio(1);                   // T5: favor MFMA-entering wave
#pragma unroll
      for (int ks = 0; ks < KS; ++ks)
#pragma unroll
        for (int fm = 0; fm < FM; ++fm)
#pragma unroll
          for (int fn = 0; fn < FN; ++fn)
            acc[fm][fn] = mfma16(a[ks][fm], b[ks][fn], acc[fm][fn]);
      __builtin_amdgcn_s_setprio(0);
      if (more) waitvm<LT>(); else waitvm<0>();
      __builtin_amdgcn_s_barrier();
      asm volatile("" ::: "memory");
      cur = (cur == 2) ? 0 : cur + 1;
      stg = (stg == 2) ? 0 : stg + 1;
    }
  } else {                       // f32 B^T fallback: BK=32, BN=128, slot 0 only
    const float* Bf = (const float*)Bp;
    for (int k0 = 0; k0 < Ktot; k0 += BK) {
#pragma unroll
      for (int i = 0; i < LA; ++i) {
        int c = i * 256 + tid;
        int row = c / CPR, part = c % CPR;
        gload16(A + (size_t)(m0 + row) * lda + k0 + part * 8,
                &As[0][(i * 256 + wid * 64) * 8]);
      }
      {
        int row = tid >> 1, kh = (tid & 1) * 16;
        const float* src = Bf + (size_t)(n0 + row) * ldb + k0 + kh;
        float4 v0 = *reinterpret_cast<const float4*>(src);
        float4 v1 = *reinterpret_cast<const float4*>(src + 4);
        float4 v2 = *reinterpret_cast<const float4*>(src + 8);
        float4 v3 = *reinterpret_cast<const float4*>(src + 12);
        short8 p0, p1;
        p0[0] = f2b(v0.x); p0[1] = f2b(v0.y); p0[2] = f2b(v0.z); p0[3] = f2b(v0.w);
        p0[4] = f2b(v1.x); p0[5] = f2b(v1.y); p0[6] = f2b(v1.z); p0[7] = f2b(v1.w);
        p1[0] = f2b(v2.x); p1[1] = f2b(v2.y); p1[2] = f2b(v2.z); p1[3] = f2b(v2.w);
        p1[4] = f2b(v3.x); p1[5] = f2b(v3.y); p1[6] = f2b(v3.z); p1[7] = f2b(v3.w);
        *reinterpret_cast<short8*>(&Bs[0][row * BK + kh])     = p0;
        *reinterpret_cast<short8*>(&Bs[0][row * BK + kh + 8]) = p1;
      }
      __syncthreads();
      short8 a[KS][FM], b[KS][FN];
#pragma unroll
      for (int ks = 0; ks < KS; ++ks) {
#pragma unroll
        for (int fm = 0; fm < FM; ++fm) {
          int row = wm + fm * 16 + (lane & 15);
          a[ks][fm] = *reinterpret_cast<const short8*>(&As[0][row * BK + (ks * 4 + (lane >> 4)) * 8]);
        }
#pragma unroll
        for (int fn = 0; fn < FN; ++fn) {
          int row = wn + fn * 16 + (lane & 15);
          b[ks][fn] = *reinterpret_cast<const short8*>(&Bs[0][row * BK + (ks * 4 + (lane >> 4)) * 8]);
        }
      }
#pragma unroll
      for (int ks = 0; ks < KS; ++ks)
#pragma unroll
        for (int fm = 0; fm < FM; ++fm)
#pragma unroll
          for (int fn = 0; fn < FN; ++fn)
            acc[fm][fn] = mfma16(a[ks][fm], b[ks][fn], acc[fm][fn]);
      __syncthreads();
    }
  }

  // ---- epilogue ----
  const size_t pbase = (KSPLIT > 1) ? (size_t)blockIdx.z * gridDim.x * BM * ldc : 0;
#pragma unroll
  for (int fm = 0; fm < FM; ++fm) {
#pragma unroll
    for (int fn = 0; fn < FN; ++fn) {
#pragma unroll
      for (int r = 0; r < 4; ++r) {
        int row = m0 + wm + fm * 16 + (lane >> 4) * 4 + r;
        int col = n0 + wn + fn * 16 + (lane & 15);
        float val = acc[fm][fn][r];
        if (BIAS) val += bias[col];
        if (RELU) val = fmaxf(val, 0.0f);
        if (OUTMODE == 0) {
          ((float*)Cv)[pbase + (size_t)row * ldc + col] = val;
        } else if (OUTMODE == 1) {
          ((u16*)Cv)[(size_t)row * ldc + col] = f2b(val);
        } else if (OUTMODE == 3) {
          ((u16*)Cv)[pbase + (size_t)row * ldc + col] = f2b(val);
        } else {
          int sel = col >> 10, cc = col & 1023;
          if (sel == 0) val *= 0.03125f;          // pre-scale q by 1/sqrt(d_model)
          ((u16*)Cv)[(size_t)sel * (LSEQ * DMODEL) + (size_t)row * DMODEL + cc] = f2b(val);
        }
      }
    }
  }
}

// ---------------- causal flash attention, KVBLK=64, async reg-staged K/V (T14) ----------------
// FUSE=1: q points at the QKV split-K bf16 partial planes sp [2][L][3072];
//         q/k/v combined (plane0+plane1, q scaled 1/32) at LDS-write time.
// FUSE=0: q/k/v separate [L][1024] bf16 buffers (q pre-scaled).
template<int FUSE>
__global__ __launch_bounds__(256) void attn_k(const u16* __restrict__ q,
    const u16* __restrict__ kmat, const u16* __restrict__ v, u16* __restrict__ o)
{
  __shared__ u16 Ks[64][72];
  __shared__ u16 Vt[64][72];
  __shared__ u16 Pl[4][16][72];
  const int tid = threadIdx.x, lane = tid & 63, wid = tid >> 6;
  const int h = blockIdx.y, qt = blockIdx.x;
  const int qw0 = qt * 64 + wid * 16;
  const int qrow = qw0 + (lane & 15);
  const size_t PLQ = (size_t)LSEQ * 3072;
  short8 aq0, aq1;
  if constexpr (FUSE) {
    const u16* qp = q + (size_t)qrow * 3072 + h * DHEAD + (lane >> 4) * 8;
    short8 a0 = *reinterpret_cast<const short8*>(qp);
    short8 b0 = *reinterpret_cast<const short8*>(qp + PLQ);
    short8 a1 = *reinterpret_cast<const short8*>(qp + 32);
    short8 b1 = *reinterpret_cast<const short8*>(qp + 32 + PLQ);
#pragma unroll
    for (int j = 0; j < 8; ++j) {
      aq0[j] = (short)f2b((b2f((u16)a0[j]) + b2f((u16)b0[j])) * 0.03125f);
      aq1[j] = (short)f2b((b2f((u16)a1[j]) + b2f((u16)b1[j])) * 0.03125f);
    }
  } else {
    aq0 = *reinterpret_cast<const short8*>(q + (size_t)qrow * DMODEL + h * DHEAD + (lane >> 4) * 8);
    aq1 = *reinterpret_cast<const short8*>(q + (size_t)qrow * DMODEL + h * DHEAD + 32 + (lane >> 4) * 8);
  }
  float m_run[4], l_run[4];
  f32x4 oacc[4] = {};
#pragma unroll
  for (int r = 0; r < 4; ++r) { m_run[r] = -1e30f; l_run[r] = 0.0f; }
  const int kvend = qt * 64 + 64;

  const int kvi = tid >> 2, c16 = (tid & 3) * 16;
  short8 kr0, kr1, vr0, vr1;
  short8 kr0b, kr1b, vr0b, vr1b;
  auto loadregs = [&](int kv0) {
    if constexpr (FUSE) {
      const u16* kp = q + (size_t)(kv0 + kvi) * 3072 + 1024 + h * DHEAD + c16;
      kr0  = *reinterpret_cast<const short8*>(kp);
      kr1  = *reinterpret_cast<const short8*>(kp + 8);
      kr0b = *reinterpret_cast<const short8*>(kp + PLQ);
      kr1b = *reinterpret_cast<const short8*>(kp + 8 + PLQ);
      const u16* vp = q + (size_t)(kv0 + kvi) * 3072 + 2048 + h * DHEAD + c16;
      vr0  = *reinterpret_cast<const short8*>(vp);
      vr1  = *reinterpret_cast<const short8*>(vp + 8);
      vr0b = *reinterpret_cast<const short8*>(vp + PLQ);
      vr1b = *reinterpret_cast<const short8*>(vp + 8 + PLQ);
    } else {
      const u16* kp = kmat + (size_t)(kv0 + kvi) * DMODEL + h * DHEAD + c16;
      kr0 = *reinterpret_cast<const short8*>(kp);
      kr1 = *reinterpret_cast<const short8*>(kp + 8);
      const u16* vp = v + (size_t)(kv0 + kvi) * DMODEL + h * DHEAD + c16;
      vr0 = *reinterpret_cast<const short8*>(vp);
      vr1 = *reinterpret_cast<const short8*>(vp + 8);
    }
  };
  loadregs(0);

  for (int kv0 = 0; kv0 < kvend; kv0 += 64) {
    __syncthreads();
    if constexpr (FUSE) {
      short8 ko0, ko1;
#pragma unroll
      for (int j = 0; j < 8; ++j) {
        ko0[j] = (short)f2b(b2f((u16)kr0[j]) + b2f((u16)kr0b[j]));
        ko1[j] = (short)f2b(b2f((u16)kr1[j]) + b2f((u16)kr1b[j]));
      }
      *reinterpret_cast<short8*>(&Ks[kvi][c16])     = ko0;
      *reinterpret_cast<short8*>(&Ks[kvi][c16 + 8]) = ko1;
#pragma unroll
      for (int j = 0; j < 8; ++j) {
        Vt[c16 + j][kvi]     = f2b(b2f((u16)vr0[j]) + b2f((u16)vr0b[j]));
        Vt[c16 + 8 + j][kvi] = f2b(b2f((u16)vr1[j]) + b2f((u16)vr1b[j]));
      }
    } else {
      *reinterpret_cast<short8*>(&Ks[kvi][c16])     = kr0;
      *reinterpret_cast<short8*>(&Ks[kvi][c16 + 8]) = kr1;
#pragma unroll
      for (int j = 0; j < 8; ++j) { Vt[c16 + j][kvi] = (u16)vr0[j]; Vt[c16 + 8 + j][kvi] = (u16)vr1[j]; }
    }
    __syncthreads();
    if (kv0 + 64 < kvend) loadregs(kv0 + 64);

    float sm[4][4];
#pragma unroll
    for (int t2 = 0; t2 < 4; ++t2) {
      short8 bk0 = *reinterpret_cast<const short8*>(&Ks[t2 * 16 + (lane & 15)][(lane >> 4) * 8]);
      short8 bk1 = *reinterpret_cast<const short8*>(&Ks[t2 * 16 + (lane & 15)][32 + (lane >> 4) * 8]);
      f32x4 s4 = {};
      s4 = mfma16(aq0, bk0, s4);
      s4 = mfma16(aq1, bk1, s4);
#pragma unroll
      for (int r = 0; r < 4; ++r) {
        int rowg = qw0 + (lane >> 4) * 4 + r;
        int colg = kv0 + t2 * 16 + (lane & 15);
        sm[t2][r] = (colg <= rowg) ? s4[r] : -1e30f;
      }
    }
    float alpha[4], p[4][4];
#pragma unroll
    for (int r = 0; r < 4; ++r) {
      float mx = fmaxf(fmaxf(sm[0][r], sm[1][r]), fmaxf(sm[2][r], sm[3][r]));
#pragma unroll
      for (int d = 1; d < 16; d <<= 1) mx = fmaxf(mx, __shfl_xor(mx, d));
      float mn = fmaxf(m_run[r], mx);
      alpha[r] = __expf(m_run[r] - mn);
      float ps = 0.0f;
#pragma unroll
      for (int t2 = 0; t2 < 4; ++t2) { p[t2][r] = __expf(sm[t2][r] - mn); ps += p[t2][r]; }
#pragma unroll
      for (int d = 1; d < 16; d <<= 1) ps += __shfl_xor(ps, d);
      l_run[r] = l_run[r] * alpha[r] + ps;
      m_run[r] = mn;
    }
#pragma unroll
    for (int fn = 0; fn < 4; ++fn) {
      f32x4 t = oacc[fn];
      t[0] *= alpha[0]; t[1] *= alpha[1]; t[2] *= alpha[2]; t[3] *= alpha[3];
      oacc[fn] = t;
    }
#pragma unroll
    for (int r = 0; r < 4; ++r) {
      int rit = (lane >> 4) * 4 + r;
#pragma unroll
      for (int t2 = 0; t2 < 4; ++t2)
        Pl[wid][rit][t2 * 16 + (lane & 15)] = f2b(p[t2][r]);
    }
    short8 pa0 = *reinterpret_cast<const short8*>(&Pl[wid][lane & 15][(lane >> 4) * 8]);
    short8 pa1 = *reinterpret_cast<const short8*>(&Pl[wid][lane & 15][32 + (lane >> 4) * 8]);
#pragma unroll
    for (int fn = 0; fn < 4; ++fn) {
      short8 bv0 = *reinterpret_cast<const short8*>(&Vt[fn * 16 + (lane & 15)][(lane >> 4) * 8]);
      short8 bv1 = *reinterpret_cast<const short8*>(&Vt[fn * 16 + (lane & 15)][32 + (lane >> 4) * 8]);
      oacc[fn] = mfma16(pa0, bv0, oacc[fn]);
      oacc[fn] = mfma16(pa1, bv1, oacc[fn]);
    }
  }
#pragma unroll
  for (int fn = 0; fn < 4; ++fn) {
#pragma unroll
    for (int r = 0; r < 4; ++r) {
      int row = qw0 + (lane >> 4) * 4 + r;
      float val = oacc[fn][r] / l_run[r];
      o[(size_t)row * DMODEL + h * DHEAD + fn * 16 + (lane & 15)] = f2b(val);
    }
  }
}

// ---------------- launch ----------------
extern "C" void kernel_launch(void* const* d_in, const int* in_sizes, int n_in,
                              void* d_out, int out_size, void* d_ws, size_t ws_size,
                              hipStream_t stream) {
  (void)in_sizes; (void)n_in; (void)out_size;
  const int*   tok    = (const int*)d_in[0];
  const float* emb    = (const float*)d_in[1];
  const float* finalb = (const float*)d_in[2];
  const float* Wq     = (const float*)d_in[3];
  const float* Wk     = (const float*)d_in[4];
  const float* Wv     = (const float*)d_in[5];
  const float* Wo     = (const float*)d_in[6];
  const float* ln1s   = (const float*)d_in[7];
  const float* ln1b   = (const float*)d_in[8];
  const float* W1     = (const float*)d_in[9];
  const float* b1     = (const float*)d_in[10];
  const float* W2     = (const float*)d_in[11];
  const float* b2     = (const float*)d_in[12];
  const float* ln2s   = (const float*)d_in[13];
  const float* ln2b   = (const float*)d_in[14];
  float* out = (float*)d_out;

  // workspace: activations
  float* x   = (float*)d_ws;                       // 4 MiB
  float* y   = x + LSEQ * DMODEL;                  // 4 MiB (scratch)
  u16* xb    = (u16*)(y + LSEQ * DMODEL);
  u16* qb    = xb + LSEQ * DMODEL;                 // fallback q/k/v
  u16* kb    = qb + LSEQ * DMODEL;
  u16* vb    = kb + LSEQ * DMODEL;
  u16* ob    = vb + LSEQ * DMODEL;
  u16* h1    = ob + LSEQ * DMODEL;                 // 8 MiB
  u16* wbase = h1 + LSEQ * DFF;
  float* woPart = (float*)h1;   // 2 f32 planes (8 MiB) — h1 free during Wo GEMM

  const size_t eQKV = (size_t)3 * DMODEL * DMODEL;
  const size_t eWO  = (size_t)DMODEL * DMODEL;
  const size_t eW1  = (size_t)DFF * DMODEL;
  const size_t eW2  = (size_t)DMODEL * DFF;
  const size_t perL = eQKV + eWO + eW1 + eW2;
  const size_t eEMB = (size_t)NVOCAB * DMODEL;
  const size_t eSP  = (size_t)2 * LSEQ * DFF;        // split-K bf16 partials (16 MiB)
  const size_t actE = (size_t)(wbase - (u16*)d_ws);
  const size_t bigNeed = (actE + NLAYER * perL + eEMB + eSP) * 2;
  const size_t midNeed = (actE + perL + eEMB) * 2;
  const int mode = ws_size >= bigNeed ? 2 : (ws_size >= midNeed ? 1 : 0);
  const int WL = (mode == 2) ? NLAYER : 1;

  u16* qkvT = wbase;
  u16* woT  = qkvT + WL * eQKV;
  u16* w1T  = woT  + WL * eWO;
  u16* w2T  = w1T  + WL * eW1;
  u16* embT = w2T  + WL * eW2;
  u16* sp   = embT + eEMB;                           // bf16 split-K partial planes

  if (mode == 2) {
    tconv_k<<<dim3(1, 16, 192), 256, 0, stream>>>(Wq, qkvT, DMODEL, DHEAD, 16, 3 * DMODEL, 0,    DMODEL * DHEAD);
    tconv_k<<<dim3(1, 16, 192), 256, 0, stream>>>(Wk, qkvT, DMODEL, DHEAD, 16, 3 * DMODEL, 1024, DMODEL * DHEAD);
    tconv_k<<<dim3(1, 16, 192), 256, 0, stream>>>(Wv, qkvT, DMODEL, DHEAD, 16, 3 * DMODEL, 2048, DMODEL * DHEAD);
    tconv_k<<<dim3(16, 16, 12), 256, 0, stream>>>(Wo, woT, DMODEL, DMODEL, 1, DMODEL, 0, DMODEL * DMODEL);
    tconv_k<<<dim3(64, 16, 12), 256, 0, stream>>>(W1, w1T, DMODEL, DFF, 1, DFF, 0, DMODEL * DFF);
    tconv_k<<<dim3(16, 64, 12), 256, 0, stream>>>(W2, w2T, DFF, DMODEL, 1, DMODEL, 0, DFF * DMODEL);
    ec_k<<<(NVOCAB * DMODEL) / 2048, 256, 0, stream>>>(emb, embT);
  } else if (mode == 1) {
    ec_k<<<(NVOCAB * DMODEL) / 2048, 256, 0, stream>>>(emb, embT);
  }

  embed_k<<<LSEQ, 256, 0, stream>>>(tok, emb, x, xb);

  for (int l = 0; l < NLAYER; ++l) {
    const float* wq  = Wq + (size_t)l * NHEAD * DMODEL * DHEAD;
    const float* wk  = Wk + (size_t)l * NHEAD * DMODEL * DHEAD;
    const float* wv  = Wv + (size_t)l * NHEAD * DMODEL * DHEAD;
    const float* wo  = Wo + (size_t)l * DMODEL * DMODEL;
    const float* w1  = W1 + (size_t)l * DMODEL * DFF;
    const float* b1l = b1 + (size_t)l * DFF;
    const float* w2  = W2 + (size_t)l * DFF * DMODEL;
    const float* b2l = b2 + (size_t)l * DMODEL;
    u16* qkvTl = qkvT + (mode == 2 ? (size_t)l * eQKV : 0);
    u16* woTl  = woT  + (mode == 2 ? (size_t)l * eWO  : 0);
    u16* w1Tl  = w1T  + (mode == 2 ? (size_t)l * eW1  : 0);
    u16* w2Tl  = w2T  + (mode == 2 ? (size_t)l * eW2  : 0);

    if (mode < 2) {
      tconv_k<<<dim3(1, 16, 16), 256, 0, stream>>>(wq, qkvTl, DMODEL, DHEAD, 16, 0, 0,    DMODEL * DHEAD);
      tconv_k<<<dim3(1, 16, 16), 256, 0, stream>>>(wk, qkvTl, DMODEL, DHEAD, 16, 0, 1024, DMODEL * DHEAD);
      tconv_k<<<dim3(1, 16, 16), 256, 0, stream>>>(wv, qkvTl, DMODEL, DHEAD, 16, 0, 2048, DMODEL * DHEAD);
      tconv_k<<<dim3(16, 16, 1), 256, 0, stream>>>(wo, woTl, DMODEL, DMODEL, 1, 0, 0, 0);
      tconv_k<<<dim3(64, 16, 1), 256, 0, stream>>>(w1, w1Tl, DMODEL, DFF, 1, 0, 0, 0);
      tconv_k<<<dim3(16, 64, 1), 256, 0, stream>>>(w2, w2Tl, DFF, DMODEL, 1, 0, 0, 0);
    }

    if (mode == 2) {
      // QKV: 128x128 BK32, split-K 2 (grid 8x24x2 = 384 blocks), bf16 partials -> sp
      gemm_bt<128, 128, 32, 0, false, false, 3, 2><<<dim3(8, 24, 2), 256, 0, stream>>>(
          xb, DMODEL, qkvTl, DMODEL, nullptr, sp, 3 * DMODEL, DMODEL);
      // attention reads the partial planes directly (fused reduce + q-scale)
      attn_k<1><<<dim3(16, 16), 256, 0, stream>>>(sp, nullptr, nullptr, ob);
    } else {
      gemm_bt<64, 64, 64, 0, false, false, 2, 1><<<dim3(16, 48), 256, 0, stream>>>(
          xb, DMODEL, qkvTl, DMODEL, nullptr, qb, DMODEL, DMODEL);
      attn_k<0><<<dim3(16, 16), 256, 0, stream>>>(qb, kb, vb, ob);
    }
    // Wo: 64x64 BK64, split-K 2 (grid 16x16x2 = 512 blocks), f32 partials -> h1 region
    gemm_bt<64, 64, 64, 0, false, false, 0, 2><<<dim3(16, 16, 2), 256, 0, stream>>>(
        ob, DMODEL, woTl, DMODEL, nullptr, woPart, DMODEL, DMODEL);
    ln_k<<<LSEQ, 256, 0, stream>>>(x, woPart, 2, nullptr,
        ln1s + (size_t)l * DMODEL, ln1b + (size_t)l * DMODEL, x, xb);
    if (mode == 2) {
      // FF1: 128x128 BK32, split-K 2 (grid 8x32x2 = 512 blocks), bf16 partials -> sp
      gemm_bt<128, 128, 32, 0, false, false, 3, 2><<<dim3(8, 32, 2), 256, 0, stream>>>(
          xb, DMODEL, w1Tl, DMODEL, nullptr, sp, DFF, DMODEL);
      ffred_k<<<(LSEQ * DFF) / 2048, 256, 0, stream>>>(sp, b1l, h1);
      // FF2: 128x128 BK32, split-K 8 (grid 8x8x8 = 512 blocks), bf16 partials -> sp
      gemm_bt<128, 128, 32, 0, false, false, 3, 8><<<dim3(8, 8, 8), 256, 0, stream>>>(
          h1, DFF, w2Tl, DFF, nullptr, sp, DMODEL, DFF);
      lnb_k<<<LSEQ, 256, 0, stream>>>(x, sp, 8, b2l,
          ln2s + (size_t)l * DMODEL, ln2b + (size_t)l * DMODEL, x, xb);
    } else {
      gemm_bt<64, 64, 64, 0, true, true, 1, 1><<<dim3(16, 64), 256, 0, stream>>>(
          xb, DMODEL, w1Tl, DMODEL, b1l, h1, DFF, DMODEL);
      gemm_bt<64, 64, 64, 0, false, false, 0, 2><<<dim3(16, 16, 2), 256, 0, stream>>>(
          h1, DFF, w2Tl, DFF, nullptr, (float*)qb, DMODEL, DFF);
      ln_k<<<LSEQ, 256, 0, stream>>>(x, (float*)qb, 2, b2l,
          ln2s + (size_t)l * DMODEL, ln2b + (size_t)l * DMODEL, x, xb);
    }
  }

  // logits = x @ emb^T + final_b
  // BM=256 (wave tile 128x64): 42.7 FLOP per LDS byte — raises the ds_read ceiling.
  // 72KB LDS -> 2 blocks/CU; grid 4x250 = 1000 blocks.
  if (mode >= 1) {
    gemm_bt<256, 128, 32, 0, true, false, 0, 1><<<dim3(4, 250), 256, 0, stream>>>(
        xb, DMODEL, embT, DMODEL, finalb, out, NVOCAB, DMODEL);
  } else {
    gemm_bt<128, 128, 32, 1, true, false, 0, 1><<<dim3(8, 250), 256, 0, stream>>>(
        xb, DMODEL, emb, DMODEL, finalb, out, NVOCAB, DMODEL);
  }
}

// Round 14
// 1758.107 us; speedup vs baseline: 1.0890x; 1.0039x over previous
//
#include <hip/hip_runtime.h>

typedef unsigned short u16;
typedef __attribute__((ext_vector_type(8))) short short8;
typedef __attribute__((ext_vector_type(4))) float f32x4;
typedef __attribute__((ext_vector_type(4))) u16 u16x4;

#define LSEQ   1024
#define DMODEL 1024
#define NHEAD  16
#define DHEAD  64
#define DFF    4096
#define NLAYER 12
#define NVOCAB 32000

__device__ __forceinline__ u16 f2b(float f) {
  union { float f; unsigned u; } x; x.f = f;
  unsigned r = x.u + 0x7fffu + ((x.u >> 16) & 1u);   // RNE
  return (u16)(r >> 16);
}
__device__ __forceinline__ float b2f(u16 u) {
  union { unsigned u; float f; } x; x.u = ((unsigned)u) << 16; return x.f;
}

__device__ __forceinline__ f32x4 mfma16(short8 a, short8 b, f32x4 c) {
  return __builtin_amdgcn_mfma_f32_16x16x32_bf16(a, b, c, 0, 0, 0);
}

// async global->LDS, 16B per lane. LDS dest = wave-uniform base + lane*16.
__device__ __forceinline__ void gload16(const u16* g, u16* l) {
  __builtin_amdgcn_global_load_lds(
      (const __attribute__((address_space(1))) void*)g,
      (__attribute__((address_space(3))) void*)l, 16, 0, 0);
}

template<int N> __device__ __forceinline__ void waitvm() {
  if constexpr (N <= 0)      asm volatile("s_waitcnt vmcnt(0)" ::: "memory");
  else if constexpr (N == 1) asm volatile("s_waitcnt vmcnt(1)" ::: "memory");
  else if constexpr (N == 2) asm volatile("s_waitcnt vmcnt(2)" ::: "memory");
  else if constexpr (N == 3) asm volatile("s_waitcnt vmcnt(3)" ::: "memory");
  else if constexpr (N == 4) asm volatile("s_waitcnt vmcnt(4)" ::: "memory");
  else if constexpr (N == 5) asm volatile("s_waitcnt vmcnt(5)" ::: "memory");
  else if constexpr (N == 6) asm volatile("s_waitcnt vmcnt(6)" ::: "memory");
  else                       asm volatile("s_waitcnt vmcnt(8)" ::: "memory");
}

// ---------------- embedding + positional encoding ----------------
__global__ __launch_bounds__(256) void embed_k(const int* __restrict__ tok,
    const float* __restrict__ emb, float* __restrict__ x, u16* __restrict__ xb)
{
  const int l = blockIdx.x;
  const int d0 = threadIdx.x * 4;
  const int t = tok[l];
  const float lf = (float)l;
  float o[4]; u16 obv[4];
#pragma unroll
  for (int j = 0; j < 4; ++j) {
    int d = d0 + j;
    int p = d >> 1;
    float ang = lf * powf(10000.0f, -(float)(2 * p) / 1024.0f);
    float pe = (d & 1) ? cosf(ang) : sinf(ang);
    float val = 2.0f * emb[(size_t)t * DMODEL + d] * 55.42562584220407f + pe; // sqrt(3072)
    o[j] = val; obv[j] = f2b(val);
  }
  *reinterpret_cast<float4*>(x + (size_t)l * DMODEL + d0) = make_float4(o[0], o[1], o[2], o[3]);
  u16x4 vb = { obv[0], obv[1], obv[2], obv[3] };
  *reinterpret_cast<u16x4*>(xb + (size_t)l * DMODEL + d0) = vb;
}

// ---------------- residual-add (+P f32 partials, +opt bias) + LayerNorm ----------------
__global__ __launch_bounds__(256) void ln_k(const float* __restrict__ xin,
    const float* __restrict__ ypart, int P, const float* __restrict__ ybias,
    const float* __restrict__ s, const float* __restrict__ b,
    float* __restrict__ xout, u16* __restrict__ xbout)
{
  const int row = blockIdx.x, tid = threadIdx.x;
  const int d0 = tid * 4;
  float4 xv = *reinterpret_cast<const float4*>(xin + (size_t)row * DMODEL + d0);
  float t0 = xv.x, t1 = xv.y, t2 = xv.z, t3 = xv.w;
#pragma unroll 2
  for (int p = 0; p < P; ++p) {
    float4 yv = *reinterpret_cast<const float4*>(ypart + (size_t)p * (LSEQ * DMODEL) + (size_t)row * DMODEL + d0);
    t0 += yv.x; t1 += yv.y; t2 += yv.z; t3 += yv.w;
  }
  if (ybias) {
    float4 bb = *reinterpret_cast<const float4*>(ybias + d0);
    t0 += bb.x; t1 += bb.y; t2 += bb.z; t3 += bb.w;
  }
  float sum = t0 + t1 + t2 + t3;
  float sq  = t0 * t0 + t1 * t1 + t2 * t2 + t3 * t3;
#pragma unroll
  for (int d = 1; d < 64; d <<= 1) { sum += __shfl_xor(sum, d); sq += __shfl_xor(sq, d); }
  __shared__ float ssum[4], ssq[4];
  const int wid = tid >> 6;
  if ((tid & 63) == 0) { ssum[wid] = sum; ssq[wid] = sq; }
  __syncthreads();
  sum = ssum[0] + ssum[1] + ssum[2] + ssum[3];
  sq  = ssq[0] + ssq[1] + ssq[2] + ssq[3];
  const float mu = sum * (1.0f / 1024.0f);
  const float var = sq * (1.0f / 1024.0f) - mu * mu;
  const float rstd = rsqrtf(var + 1e-5f);
  float4 sv = *reinterpret_cast<const float4*>(s + d0);
  float4 bv = *reinterpret_cast<const float4*>(b + d0);
  float o0 = (t0 - mu) * rstd * sv.x + bv.x;
  float o1 = (t1 - mu) * rstd * sv.y + bv.y;
  float o2 = (t2 - mu) * rstd * sv.z + bv.z;
  float o3 = (t3 - mu) * rstd * sv.w + bv.w;
  *reinterpret_cast<float4*>(xout + (size_t)row * DMODEL + d0) = make_float4(o0, o1, o2, o3);
  u16x4 vb = { f2b(o0), f2b(o1), f2b(o2), f2b(o3) };
  *reinterpret_cast<u16x4*>(xbout + (size_t)row * DMODEL + d0) = vb;
}

// ---------------- residual-add (+P bf16 partial planes, +opt bias) + LayerNorm ----------------
__global__ __launch_bounds__(256) void lnb_k(const float* __restrict__ xin,
    const u16* __restrict__ ypart, int P, const float* __restrict__ ybias,
    const float* __restrict__ s, const float* __restrict__ b,
    float* __restrict__ xout, u16* __restrict__ xbout)
{
  const int row = blockIdx.x, tid = threadIdx.x;
  const int d0 = tid * 4;
  float4 xv = *reinterpret_cast<const float4*>(xin + (size_t)row * DMODEL + d0);
  float t0 = xv.x, t1 = xv.y, t2 = xv.z, t3 = xv.w;
#pragma unroll 4
  for (int p = 0; p < P; ++p) {
    u16x4 yv = *reinterpret_cast<const u16x4*>(ypart + (size_t)p * (LSEQ * DMODEL) + (size_t)row * DMODEL + d0);
    t0 += b2f(yv[0]); t1 += b2f(yv[1]); t2 += b2f(yv[2]); t3 += b2f(yv[3]);
  }
  if (ybias) {
    float4 bb = *reinterpret_cast<const float4*>(ybias + d0);
    t0 += bb.x; t1 += bb.y; t2 += bb.z; t3 += bb.w;
  }
  float sum = t0 + t1 + t2 + t3;
  float sq  = t0 * t0 + t1 * t1 + t2 * t2 + t3 * t3;
#pragma unroll
  for (int d = 1; d < 64; d <<= 1) { sum += __shfl_xor(sum, d); sq += __shfl_xor(sq, d); }
  __shared__ float ssum[4], ssq[4];
  const int wid = tid >> 6;
  if ((tid & 63) == 0) { ssum[wid] = sum; ssq[wid] = sq; }
  __syncthreads();
  sum = ssum[0] + ssum[1] + ssum[2] + ssum[3];
  sq  = ssq[0] + ssq[1] + ssq[2] + ssq[3];
  const float mu = sum * (1.0f / 1024.0f);
  const float var = sq * (1.0f / 1024.0f) - mu * mu;
  const float rstd = rsqrtf(var + 1e-5f);
  float4 sv = *reinterpret_cast<const float4*>(s + d0);
  float4 bv = *reinterpret_cast<const float4*>(b + d0);
  float o0 = (t0 - mu) * rstd * sv.x + bv.x;
  float o1 = (t1 - mu) * rstd * sv.y + bv.y;
  float o2 = (t2 - mu) * rstd * sv.z + bv.z;
  float o3 = (t3 - mu) * rstd * sv.w + bv.w;
  *reinterpret_cast<float4*>(xout + (size_t)row * DMODEL + d0) = make_float4(o0, o1, o2, o3);
  u16x4 vb = { f2b(o0), f2b(o1), f2b(o2), f2b(o3) };
  *reinterpret_cast<u16x4*>(xbout + (size_t)row * DMODEL + d0) = vb;
}

// ---------------- split-K reduce: FF1 (2 bf16 planes [L][4096] + bias, ReLU -> h1) ----------------
__global__ __launch_bounds__(256) void ffred_k(const u16* __restrict__ sp,
    const float* __restrict__ bias, u16* __restrict__ out)
{
  const size_t idx = ((size_t)blockIdx.x * 256 + threadIdx.x) * 8;
  const int c0 = (int)(idx % DFF);
  short8 a = *reinterpret_cast<const short8*>(sp + idx);
  short8 b = *reinterpret_cast<const short8*>(sp + (size_t)LSEQ * DFF + idx);
  short8 o;
#pragma unroll
  for (int j = 0; j < 8; ++j) {
    float val = b2f((u16)a[j]) + b2f((u16)b[j]) + bias[c0 + j];
    o[j] = (short)f2b(fmaxf(val, 0.0f));
  }
  *reinterpret_cast<short8*>(out + idx) = o;
}

// ---------------- transpose-convert: f32 in[R][C] -> bf16 out rows ----------------
__global__ __launch_bounds__(256) void tconv_k(const float* __restrict__ in, u16* __restrict__ out,
                                               int R, int C, int zper, int lstride, int obase, int zstride)
{
  __shared__ float t[64][65];
  const int rt = blockIdx.y * 64, ct = blockIdx.x * 64;
  const int z = blockIdx.z;
  in += (size_t)z * zstride;
  const int tr = threadIdx.x >> 4, tc = threadIdx.x & 15;
#pragma unroll
  for (int i = 0; i < 4; ++i) {
    int r = i * 16 + tr;
    float4 v = *reinterpret_cast<const float4*>(in + (size_t)(rt + r) * C + ct + tc * 4);
    t[r][tc * 4 + 0] = v.x; t[r][tc * 4 + 1] = v.y;
    t[r][tc * 4 + 2] = v.z; t[r][tc * 4 + 3] = v.w;
  }
  __syncthreads();
  const size_t orow0 = (size_t)(z / zper) * lstride + (size_t)(z % zper) * C + obase + ct;
#pragma unroll
  for (int i = 0; i < 4; ++i) {
    int c = i * 16 + tr;
    u16x4 o;
    o[0] = f2b(t[tc * 4 + 0][c]); o[1] = f2b(t[tc * 4 + 1][c]);
    o[2] = f2b(t[tc * 4 + 2][c]); o[3] = f2b(t[tc * 4 + 3][c]);
    *reinterpret_cast<u16x4*>(out + (orow0 + c) * R + rt + tc * 4) = o;
  }
}

// ---------------- elementwise convert f32 -> bf16 ----------------
__global__ __launch_bounds__(256) void ec_k(const float* __restrict__ in, u16* __restrict__ out)
{
  const size_t i = ((size_t)blockIdx.x * 256 + threadIdx.x) * 8;
  float4 a = *reinterpret_cast<const float4*>(in + i);
  float4 b = *reinterpret_cast<const float4*>(in + i + 4);
  short8 o;
  o[0] = f2b(a.x); o[1] = f2b(a.y); o[2] = f2b(a.z); o[3] = f2b(a.w);
  o[4] = f2b(b.x); o[5] = f2b(b.y); o[6] = f2b(b.z); o[7] = f2b(b.w);
  *reinterpret_cast<short8*>(out + i) = o;
}

// ---------------- bf16 MFMA GEMM, 3-stage counted-vmcnt pipeline ----------------
// C[M,N] = act(A[M,K] * Bt[N,K]^T + bias); grid: x = M tiles, y = N tiles, z = K split.
// Stride-aware bank swizzle: sw(row) = ((row*CPR)>>3) & (CPR-1).
// BSRC 0: A and B via global_load_lds into 3 slots, counted vmcnt (T4) + swizzle (T2)
//         + s_setprio around the MFMA cluster (T5).
// BSRC 1: f32 B^T reg-staged fallback (BK=32, BN=128), classic loop (slot 0 only).
// OUTMODE: 0 = f32 (KSPLIT>1: partial plane per z); 1 = bf16; 2 = QKV triple (q pre-scaled 1/32);
//          3 = bf16 partial plane per z (KSPLIT>1)
template<int BM, int BN, int BK, int BSRC, bool BIAS, bool RELU, int OUTMODE, int KSPLIT>
__global__ __launch_bounds__(256, 2) void gemm_bt(
    const u16* __restrict__ A, int lda,
    const void* __restrict__ Bp, int ldb,
    const float* __restrict__ bias,
    void* __restrict__ Cv, int ldc, int Ktot)
{
  constexpr int CPR = BK / 8;            // 16B chunks per row
  constexpr int SWM = CPR - 1;
  constexpr int LA = (BM * CPR) / 256;   // A loads/thread per K-tile
  constexpr int LB = (BN * CPR) / 256;   // B loads/thread per K-tile
  constexpr int LT = LA + LB;
  __shared__ u16 As[3][BM * BK];
  __shared__ u16 Bs[3][BN * BK];
  const int tid = threadIdx.x, lane = tid & 63, wid = tid >> 6;
  // chunked XCD swizzle on (x,y) (bijective: gx*gy is a multiple of 8 in all uses)
  const int nwg = gridDim.x * gridDim.y;
  const int flat = blockIdx.y * gridDim.x + blockIdx.x;
  const int qq = nwg >> 3;
  const int ni = (flat & 7) * qq + (flat >> 3);
  const int m0 = (ni % gridDim.x) * BM, n0 = (ni / gridDim.x) * BN;
  const int kbase = (KSPLIT > 1) ? blockIdx.z * (Ktot / KSPLIT) : 0;
  const int klen  = (KSPLIT > 1) ? (Ktot / KSPLIT) : Ktot;
  constexpr int FM = BM / 32, FN = BN / 32;
  constexpr int KS = BK / 32;
  const int wm = (wid >> 1) * (BM / 2), wn = (wid & 1) * (BN / 2);
  f32x4 acc[FM][FN] = {};

  if constexpr (BSRC == 0) {
    const u16* Bt = (const u16*)Bp;
    auto stage = [&](int slot, int k0) {
#pragma unroll
      for (int i = 0; i < LA; ++i) {
        int c = i * 256 + tid;
        int row = c / CPR, p0 = c % CPR;
        int part = p0 ^ (((row * CPR) >> 3) & SWM);
        gload16(A + (size_t)(m0 + row) * lda + k0 + part * 8,
                &As[slot][(i * 256 + wid * 64) * 8]);
      }
#pragma unroll
      for (int i = 0; i < LB; ++i) {
        int c = i * 256 + tid;
        int row = c / CPR, p0 = c % CPR;
        int part = p0 ^ (((row * CPR) >> 3) & SWM);
        gload16(Bt + (size_t)(n0 + row) * ldb + k0 + part * 8,
                &Bs[slot][(i * 256 + wid * 64) * 8]);
      }
    };

    const int NT = klen / BK;
    stage(0, kbase);
    stage(1, kbase + BK);
    waitvm<LT>();                        // tile 0 landed, tile 1 in flight
    __builtin_amdgcn_s_barrier();
    asm volatile("" ::: "memory");

    int cur = 0, stg = 2;
    for (int t = 0; t < NT; ++t) {
      const bool more = (t + 2 < NT);
      if (more) stage(stg, kbase + (t + 2) * BK);      // tile t+2 issued; stays in flight
      asm volatile("" ::: "memory");
      short8 a[KS][FM], b[KS][FN];
#pragma unroll
      for (int ks = 0; ks < KS; ++ks) {
#pragma unroll
        for (int fm = 0; fm < FM; ++fm) {
          int row = wm + fm * 16 + (lane & 15);
          int pidx = (ks * 4 + (lane >> 4)) ^ (((row * CPR) >> 3) & SWM);
          a[ks][fm] = *reinterpret_cast<const short8*>(&As[cur][row * BK + pidx * 8]);
        }
#pragma unroll
        for (int fn = 0; fn < FN; ++fn) {
          int row = wn + fn * 16 + (lane & 15);
          int pidx = (ks * 4 + (lane >> 4)) ^ (((row * CPR) >> 3) & SWM);
          b[ks][fn] = *reinterpret_cast<const short8*>(&Bs[cur][row * BK + pidx * 8]);
        }
      }
      __builtin_amdgcn_s_setprio(1);                   // T5: favor MFMA-entering wave
#pragma unroll
      for (int ks = 0; ks < KS; ++ks)
#pragma unroll
        for (int fm = 0; fm < FM; ++fm)
#pragma unroll
          for (int fn = 0; fn < FN; ++fn)
            acc[fm][fn] = mfma16(a[ks][fm], b[ks][fn], acc[fm][fn]);
      __builtin_amdgcn_s_setprio(0);
      if (more) waitvm<LT>(); else waitvm<0>();
      __builtin_amdgcn_s_barrier();
      asm volatile("" ::: "memory");
      cur = (cur == 2) ? 0 : cur + 1;
      stg = (stg == 2) ? 0 : stg + 1;
    }
  } else {                       // f32 B^T fallback: BK=32, BN=128, slot 0 only
    const float* Bf = (const float*)Bp;
    for (int k0 = 0; k0 < Ktot; k0 += BK) {
#pragma unroll
      for (int i = 0; i < LA; ++i) {
        int c = i * 256 + tid;
        int row = c / CPR, part = c % CPR;
        gload16(A + (size_t)(m0 + row) * lda + k0 + part * 8,
                &As[0][(i * 256 + wid * 64) * 8]);
      }
      {
        int row = tid >> 1, kh = (tid & 1) * 16;
        const float* src = Bf + (size_t)(n0 + row) * ldb + k0 + kh;
        float4 v0 = *reinterpret_cast<const float4*>(src);
        float4 v1 = *reinterpret_cast<const float4*>(src + 4);
        float4 v2 = *reinterpret_cast<const float4*>(src + 8);
        float4 v3 = *reinterpret_cast<const float4*>(src + 12);
        short8 p0, p1;
        p0[0] = f2b(v0.x); p0[1] = f2b(v0.y); p0[2] = f2b(v0.z); p0[3] = f2b(v0.w);
        p0[4] = f2b(v1.x); p0[5] = f2b(v1.y); p0[6] = f2b(v1.z); p0[7] = f2b(v1.w);
        p1[0] = f2b(v2.x); p1[1] = f2b(v2.y); p1[2] = f2b(v2.z); p1[3] = f2b(v2.w);
        p1[4] = f2b(v3.x); p1[5] = f2b(v3.y); p1[6] = f2b(v3.z); p1[7] = f2b(v3.w);
        *reinterpret_cast<short8*>(&Bs[0][row * BK + kh])     = p0;
        *reinterpret_cast<short8*>(&Bs[0][row * BK + kh + 8]) = p1;
      }
      __syncthreads();
      short8 a[KS][FM], b[KS][FN];
#pragma unroll
      for (int ks = 0; ks < KS; ++ks) {
#pragma unroll
        for (int fm = 0; fm < FM; ++fm) {
          int row = wm + fm * 16 + (lane & 15);
          a[ks][fm] = *reinterpret_cast<const short8*>(&As[0][row * BK + (ks * 4 + (lane >> 4)) * 8]);
        }
#pragma unroll
        for (int fn = 0; fn < FN; ++fn) {
          int row = wn + fn * 16 + (lane & 15);
          b[ks][fn] = *reinterpret_cast<const short8*>(&Bs[0][row * BK + (ks * 4 + (lane >> 4)) * 8]);
        }
      }
#pragma unroll
      for (int ks = 0; ks < KS; ++ks)
#pragma unroll
        for (int fm = 0; fm < FM; ++fm)
#pragma unroll
          for (int fn = 0; fn < FN; ++fn)
            acc[fm][fn] = mfma16(a[ks][fm], b[ks][fn], acc[fm][fn]);
      __syncthreads();
    }
  }

  // ---- epilogue ----
  const size_t pbase = (KSPLIT > 1) ? (size_t)blockIdx.z * gridDim.x * BM * ldc : 0;
#pragma unroll
  for (int fm = 0; fm < FM; ++fm) {
#pragma unroll
    for (int fn = 0; fn < FN; ++fn) {
#pragma unroll
      for (int r = 0; r < 4; ++r) {
        int row = m0 + wm + fm * 16 + (lane >> 4) * 4 + r;
        int col = n0 + wn + fn * 16 + (lane & 15);
        float val = acc[fm][fn][r];
        if (BIAS) val += bias[col];
        if (RELU) val = fmaxf(val, 0.0f);
        if (OUTMODE == 0) {
          ((float*)Cv)[pbase + (size_t)row * ldc + col] = val;
        } else if (OUTMODE == 1) {
          ((u16*)Cv)[(size_t)row * ldc + col] = f2b(val);
        } else if (OUTMODE == 3) {
          ((u16*)Cv)[pbase + (size_t)row * ldc + col] = f2b(val);
        } else {
          int sel = col >> 10, cc = col & 1023;
          if (sel == 0) val *= 0.03125f;          // pre-scale q by 1/sqrt(d_model)
          ((u16*)Cv)[(size_t)sel * (LSEQ * DMODEL) + (size_t)row * DMODEL + cc] = f2b(val);
        }
      }
    }
  }
}

// ---------------- causal flash attention, KVBLK=64, async reg-staged K/V (T14) ----------------
// FUSE=1: q points at the QKV split-K bf16 partial planes sp [2][L][3072];
//         q/k/v combined (plane0+plane1, q scaled 1/32) at LDS-write time.
// FUSE=0: q/k/v separate [L][1024] bf16 buffers (q pre-scaled).
template<int FUSE>
__global__ __launch_bounds__(256) void attn_k(const u16* __restrict__ q,
    const u16* __restrict__ kmat, const u16* __restrict__ v, u16* __restrict__ o)
{
  __shared__ u16 Ks[64][72];
  __shared__ u16 Vt[64][72];
  __shared__ u16 Pl[4][16][72];
  const int tid = threadIdx.x, lane = tid & 63, wid = tid >> 6;
  const int h = blockIdx.y, qt = blockIdx.x;
  const int qw0 = qt * 64 + wid * 16;
  const int qrow = qw0 + (lane & 15);
  const size_t PLQ = (size_t)LSEQ * 3072;
  short8 aq0, aq1;
  if constexpr (FUSE) {
    const u16* qp = q + (size_t)qrow * 3072 + h * DHEAD + (lane >> 4) * 8;
    short8 a0 = *reinterpret_cast<const short8*>(qp);
    short8 b0 = *reinterpret_cast<const short8*>(qp + PLQ);
    short8 a1 = *reinterpret_cast<const short8*>(qp + 32);
    short8 b1 = *reinterpret_cast<const short8*>(qp + 32 + PLQ);
#pragma unroll
    for (int j = 0; j < 8; ++j) {
      aq0[j] = (short)f2b((b2f((u16)a0[j]) + b2f((u16)b0[j])) * 0.03125f);
      aq1[j] = (short)f2b((b2f((u16)a1[j]) + b2f((u16)b1[j])) * 0.03125f);
    }
  } else {
    aq0 = *reinterpret_cast<const short8*>(q + (size_t)qrow * DMODEL + h * DHEAD + (lane >> 4) * 8);
    aq1 = *reinterpret_cast<const short8*>(q + (size_t)qrow * DMODEL + h * DHEAD + 32 + (lane >> 4) * 8);
  }
  float m_run[4], l_run[4];
  f32x4 oacc[4] = {};
#pragma unroll
  for (int r = 0; r < 4; ++r) { m_run[r] = -1e30f; l_run[r] = 0.0f; }
  const int kvend = qt * 64 + 64;

  const int kvi = tid >> 2, c16 = (tid & 3) * 16;
  short8 kr0, kr1, vr0, vr1;
  short8 kr0b, kr1b, vr0b, vr1b;
  auto loadregs = [&](int kv0) {
    if constexpr (FUSE) {
      const u16* kp = q + (size_t)(kv0 + kvi) * 3072 + 1024 + h * DHEAD + c16;
      kr0  = *reinterpret_cast<const short8*>(kp);
      kr1  = *reinterpret_cast<const short8*>(kp + 8);
      kr0b = *reinterpret_cast<const short8*>(kp + PLQ);
      kr1b = *reinterpret_cast<const short8*>(kp + 8 + PLQ);
      const u16* vp = q + (size_t)(kv0 + kvi) * 3072 + 2048 + h * DHEAD + c16;
      vr0  = *reinterpret_cast<const short8*>(vp);
      vr1  = *reinterpret_cast<const short8*>(vp + 8);
      vr0b = *reinterpret_cast<const short8*>(vp + PLQ);
      vr1b = *reinterpret_cast<const short8*>(vp + 8 + PLQ);
    } else {
      const u16* kp = kmat + (size_t)(kv0 + kvi) * DMODEL + h * DHEAD + c16;
      kr0 = *reinterpret_cast<const short8*>(kp);
      kr1 = *reinterpret_cast<const short8*>(kp + 8);
      const u16* vp = v + (size_t)(kv0 + kvi) * DMODEL + h * DHEAD + c16;
      vr0 = *reinterpret_cast<const short8*>(vp);
      vr1 = *reinterpret_cast<const short8*>(vp + 8);
    }
  };
  loadregs(0);

  for (int kv0 = 0; kv0 < kvend; kv0 += 64) {
    __syncthreads();
    if constexpr (FUSE) {
      short8 ko0, ko1;
#pragma unroll
      for (int j = 0; j < 8; ++j) {
        ko0[j] = (short)f2b(b2f((u16)kr0[j]) + b2f((u16)kr0b[j]));
        ko1[j] = (short)f2b(b2f((u16)kr1[j]) + b2f((u16)kr1b[j]));
      }
      *reinterpret_cast<short8*>(&Ks[kvi][c16])     = ko0;
      *reinterpret_cast<short8*>(&Ks[kvi][c16 + 8]) = ko1;
#pragma unroll
      for (int j = 0; j < 8; ++j) {
        Vt[c16 + j][kvi]     = f2b(b2f((u16)vr0[j]) + b2f((u16)vr0b[j]));
        Vt[c16 + 8 + j][kvi] = f2b(b2f((u16)vr1[j]) + b2f((u16)vr1b[j]));
      }
    } else {
      *reinterpret_cast<short8*>(&Ks[kvi][c16])     = kr0;
      *reinterpret_cast<short8*>(&Ks[kvi][c16 + 8]) = kr1;
#pragma unroll
      for (int j = 0; j < 8; ++j) { Vt[c16 + j][kvi] = (u16)vr0[j]; Vt[c16 + 8 + j][kvi] = (u16)vr1[j]; }
    }
    __syncthreads();
    if (kv0 + 64 < kvend) loadregs(kv0 + 64);

    float sm[4][4];
#pragma unroll
    for (int t2 = 0; t2 < 4; ++t2) {
      short8 bk0 = *reinterpret_cast<const short8*>(&Ks[t2 * 16 + (lane & 15)][(lane >> 4) * 8]);
      short8 bk1 = *reinterpret_cast<const short8*>(&Ks[t2 * 16 + (lane & 15)][32 + (lane >> 4) * 8]);
      f32x4 s4 = {};
      s4 = mfma16(aq0, bk0, s4);
      s4 = mfma16(aq1, bk1, s4);
#pragma unroll
      for (int r = 0; r < 4; ++r) {
        int rowg = qw0 + (lane >> 4) * 4 + r;
        int colg = kv0 + t2 * 16 + (lane & 15);
        sm[t2][r] = (colg <= rowg) ? s4[r] : -1e30f;
      }
    }
    float alpha[4], p[4][4];
#pragma unroll
    for (int r = 0; r < 4; ++r) {
      float mx = fmaxf(fmaxf(sm[0][r], sm[1][r]), fmaxf(sm[2][r], sm[3][r]));
#pragma unroll
      for (int d = 1; d < 16; d <<= 1) mx = fmaxf(mx, __shfl_xor(mx, d));
      float mn = fmaxf(m_run[r], mx);
      alpha[r] = __expf(m_run[r] - mn);
      float ps = 0.0f;
#pragma unroll
      for (int t2 = 0; t2 < 4; ++t2) { p[t2][r] = __expf(sm[t2][r] - mn); ps += p[t2][r]; }
#pragma unroll
      for (int d = 1; d < 16; d <<= 1) ps += __shfl_xor(ps, d);
      l_run[r] = l_run[r] * alpha[r] + ps;
      m_run[r] = mn;
    }
#pragma unroll
    for (int fn = 0; fn < 4; ++fn) {
      f32x4 t = oacc[fn];
      t[0] *= alpha[0]; t[1] *= alpha[1]; t[2] *= alpha[2]; t[3] *= alpha[3];
      oacc[fn] = t;
    }
#pragma unroll
    for (int r = 0; r < 4; ++r) {
      int rit = (lane >> 4) * 4 + r;
#pragma unroll
      for (int t2 = 0; t2 < 4; ++t2)
        Pl[wid][rit][t2 * 16 + (lane & 15)] = f2b(p[t2][r]);
    }
    short8 pa0 = *reinterpret_cast<const short8*>(&Pl[wid][lane & 15][(lane >> 4) * 8]);
    short8 pa1 = *reinterpret_cast<const short8*>(&Pl[wid][lane & 15][32 + (lane >> 4) * 8]);
#pragma unroll
    for (int fn = 0; fn < 4; ++fn) {
      short8 bv0 = *reinterpret_cast<const short8*>(&Vt[fn * 16 + (lane & 15)][(lane >> 4) * 8]);
      short8 bv1 = *reinterpret_cast<const short8*>(&Vt[fn * 16 + (lane & 15)][32 + (lane >> 4) * 8]);
      oacc[fn] = mfma16(pa0, bv0, oacc[fn]);
      oacc[fn] = mfma16(pa1, bv1, oacc[fn]);
    }
  }
#pragma unroll
  for (int fn = 0; fn < 4; ++fn) {
#pragma unroll
    for (int r = 0; r < 4; ++r) {
      int row = qw0 + (lane >> 4) * 4 + r;
      float val = oacc[fn][r] / l_run[r];
      o[(size_t)row * DMODEL + h * DHEAD + fn * 16 + (lane & 15)] = f2b(val);
    }
  }
}

// ---------------- launch ----------------
extern "C" void kernel_launch(void* const* d_in, const int* in_sizes, int n_in,
                              void* d_out, int out_size, void* d_ws, size_t ws_size,
                              hipStream_t stream) {
  (void)in_sizes; (void)n_in; (void)out_size;
  const int*   tok    = (const int*)d_in[0];
  const float* emb    = (const float*)d_in[1];
  const float* finalb = (const float*)d_in[2];
  const float* Wq     = (const float*)d_in[3];
  const float* Wk     = (const float*)d_in[4];
  const float* Wv     = (const float*)d_in[5];
  const float* Wo     = (const float*)d_in[6];
  const float* ln1s   = (const float*)d_in[7];
  const float* ln1b   = (const float*)d_in[8];
  const float* W1     = (const float*)d_in[9];
  const float* b1     = (const float*)d_in[10];
  const float* W2     = (const float*)d_in[11];
  const float* b2     = (const float*)d_in[12];
  const float* ln2s   = (const float*)d_in[13];
  const float* ln2b   = (const float*)d_in[14];
  float* out = (float*)d_out;

  // workspace: activations
  float* x   = (float*)d_ws;                       // 4 MiB
  float* y   = x + LSEQ * DMODEL;                  // 4 MiB (scratch)
  u16* xb    = (u16*)(y + LSEQ * DMODEL);
  u16* qb    = xb + LSEQ * DMODEL;                 // fallback q/k/v
  u16* kb    = qb + LSEQ * DMODEL;
  u16* vb    = kb + LSEQ * DMODEL;
  u16* ob    = vb + LSEQ * DMODEL;
  u16* h1    = ob + LSEQ * DMODEL;                 // 8 MiB
  u16* wbase = h1 + LSEQ * DFF;
  u16* woPartB = h1;            // 4 bf16 planes (8 MiB) — h1 free during Wo GEMM

  const size_t eQKV = (size_t)3 * DMODEL * DMODEL;
  const size_t eWO  = (size_t)DMODEL * DMODEL;
  const size_t eW1  = (size_t)DFF * DMODEL;
  const size_t eW2  = (size_t)DMODEL * DFF;
  const size_t perL = eQKV + eWO + eW1 + eW2;
  const size_t eEMB = (size_t)NVOCAB * DMODEL;
  const size_t eSP  = (size_t)2 * LSEQ * DFF;        // split-K bf16 partials (16 MiB)
  const size_t actE = (size_t)(wbase - (u16*)d_ws);
  const size_t bigNeed = (actE + NLAYER * perL + eEMB + eSP) * 2;
  const size_t midNeed = (actE + perL + eEMB) * 2;
  const int mode = ws_size >= bigNeed ? 2 : (ws_size >= midNeed ? 1 : 0);
  const int WL = (mode == 2) ? NLAYER : 1;

  u16* qkvT = wbase;
  u16* woT  = qkvT + WL * eQKV;
  u16* w1T  = woT  + WL * eWO;
  u16* w2T  = w1T  + WL * eW1;
  u16* embT = w2T  + WL * eW2;
  u16* sp   = embT + eEMB;                           // bf16 split-K partial planes

  if (mode == 2) {
    tconv_k<<<dim3(1, 16, 192), 256, 0, stream>>>(Wq, qkvT, DMODEL, DHEAD, 16, 3 * DMODEL, 0,    DMODEL * DHEAD);
    tconv_k<<<dim3(1, 16, 192), 256, 0, stream>>>(Wk, qkvT, DMODEL, DHEAD, 16, 3 * DMODEL, 1024, DMODEL * DHEAD);
    tconv_k<<<dim3(1, 16, 192), 256, 0, stream>>>(Wv, qkvT, DMODEL, DHEAD, 16, 3 * DMODEL, 2048, DMODEL * DHEAD);
    tconv_k<<<dim3(16, 16, 12), 256, 0, stream>>>(Wo, woT, DMODEL, DMODEL, 1, DMODEL, 0, DMODEL * DMODEL);
    tconv_k<<<dim3(64, 16, 12), 256, 0, stream>>>(W1, w1T, DMODEL, DFF, 1, DFF, 0, DMODEL * DFF);
    tconv_k<<<dim3(16, 64, 12), 256, 0, stream>>>(W2, w2T, DFF, DMODEL, 1, DMODEL, 0, DFF * DMODEL);
    ec_k<<<(NVOCAB * DMODEL) / 2048, 256, 0, stream>>>(emb, embT);
  } else if (mode == 1) {
    ec_k<<<(NVOCAB * DMODEL) / 2048, 256, 0, stream>>>(emb, embT);
  }

  embed_k<<<LSEQ, 256, 0, stream>>>(tok, emb, x, xb);

  for (int l = 0; l < NLAYER; ++l) {
    const float* wq  = Wq + (size_t)l * NHEAD * DMODEL * DHEAD;
    const float* wk  = Wk + (size_t)l * NHEAD * DMODEL * DHEAD;
    const float* wv  = Wv + (size_t)l * NHEAD * DMODEL * DHEAD;
    const float* wo  = Wo + (size_t)l * DMODEL * DMODEL;
    const float* w1  = W1 + (size_t)l * DMODEL * DFF;
    const float* b1l = b1 + (size_t)l * DFF;
    const float* w2  = W2 + (size_t)l * DFF * DMODEL;
    const float* b2l = b2 + (size_t)l * DMODEL;
    u16* qkvTl = qkvT + (mode == 2 ? (size_t)l * eQKV : 0);
    u16* woTl  = woT  + (mode == 2 ? (size_t)l * eWO  : 0);
    u16* w1Tl  = w1T  + (mode == 2 ? (size_t)l * eW1  : 0);
    u16* w2Tl  = w2T  + (mode == 2 ? (size_t)l * eW2  : 0);

    if (mode < 2) {
      tconv_k<<<dim3(1, 16, 16), 256, 0, stream>>>(wq, qkvTl, DMODEL, DHEAD, 16, 0, 0,    DMODEL * DHEAD);
      tconv_k<<<dim3(1, 16, 16), 256, 0, stream>>>(wk, qkvTl, DMODEL, DHEAD, 16, 0, 1024, DMODEL * DHEAD);
      tconv_k<<<dim3(1, 16, 16), 256, 0, stream>>>(wv, qkvTl, DMODEL, DHEAD, 16, 0, 2048, DMODEL * DHEAD);
      tconv_k<<<dim3(16, 16, 1), 256, 0, stream>>>(wo, woTl, DMODEL, DMODEL, 1, 0, 0, 0);
      tconv_k<<<dim3(64, 16, 1), 256, 0, stream>>>(w1, w1Tl, DMODEL, DFF, 1, 0, 0, 0);
      tconv_k<<<dim3(16, 64, 1), 256, 0, stream>>>(w2, w2Tl, DFF, DMODEL, 1, 0, 0, 0);
    }

    if (mode == 2) {
      // QKV: 128x128 BK32, split-K 2 (grid 8x24x2 = 384 blocks), bf16 partials -> sp
      gemm_bt<128, 128, 32, 0, false, false, 3, 2><<<dim3(8, 24, 2), 256, 0, stream>>>(
          xb, DMODEL, qkvTl, DMODEL, nullptr, sp, 3 * DMODEL, DMODEL);
      // attention reads the partial planes directly (fused reduce + q-scale)
      attn_k<1><<<dim3(16, 16), 256, 0, stream>>>(sp, nullptr, nullptr, ob);
      // Wo: 128x64 BK32, split-K 4 (grid 8x16x4 = 512 blocks, 21.8 FLOP/B, 4 blocks/CU),
      //     bf16 partials -> h1 region (dead until ffred)
      gemm_bt<128, 64, 32, 0, false, false, 3, 4><<<dim3(8, 16, 4), 256, 0, stream>>>(
          ob, DMODEL, woTl, DMODEL, nullptr, woPartB, DMODEL, DMODEL);
      lnb_k<<<LSEQ, 256, 0, stream>>>(x, woPartB, 4, nullptr,
          ln1s + (size_t)l * DMODEL, ln1b + (size_t)l * DMODEL, x, xb);
      // FF1: 128x128 BK32, split-K 2 (grid 8x32x2 = 512 blocks), bf16 partials -> sp
      gemm_bt<128, 128, 32, 0, false, false, 3, 2><<<dim3(8, 32, 2), 256, 0, stream>>>(
          xb, DMODEL, w1Tl, DMODEL, nullptr, sp, DFF, DMODEL);
      ffred_k<<<(LSEQ * DFF) / 2048, 256, 0, stream>>>(sp, b1l, h1);
      // FF2: 128x128 BK32, split-K 8 (grid 8x8x8 = 512 blocks), bf16 partials -> sp
      gemm_bt<128, 128, 32, 0, false, false, 3, 8><<<dim3(8, 8, 8), 256, 0, stream>>>(
          h1, DFF, w2Tl, DFF, nullptr, sp, DMODEL, DFF);
      lnb_k<<<LSEQ, 256, 0, stream>>>(x, sp, 8, b2l,
          ln2s + (size_t)l * DMODEL, ln2b + (size_t)l * DMODEL, x, xb);
    } else {
      gemm_bt<64, 64, 64, 0, false, false, 2, 1><<<dim3(16, 48), 256, 0, stream>>>(
          xb, DMODEL, qkvTl, DMODEL, nullptr, qb, DMODEL, DMODEL);
      attn_k<0><<<dim3(16, 16), 256, 0, stream>>>(qb, kb, vb, ob);
      gemm_bt<64, 64, 64, 0, false, false, 0, 2><<<dim3(16, 16, 2), 256, 0, stream>>>(
          ob, DMODEL, woTl, DMODEL, nullptr, (float*)h1, DMODEL, DMODEL);
      ln_k<<<LSEQ, 256, 0, stream>>>(x, (float*)h1, 2, nullptr,
          ln1s + (size_t)l * DMODEL, ln1b + (size_t)l * DMODEL, x, xb);
      gemm_bt<64, 64, 64, 0, true, true, 1, 1><<<dim3(16, 64), 256, 0, stream>>>(
          xb, DMODEL, w1Tl, DMODEL, b1l, h1, DFF, DMODEL);
      gemm_bt<64, 64, 64, 0, false, false, 0, 2><<<dim3(16, 16, 2), 256, 0, stream>>>(
          h1, DFF, w2Tl, DFF, nullptr, (float*)qb, DMODEL, DFF);
      ln_k<<<LSEQ, 256, 0, stream>>>(x, (float*)qb, 2, b2l,
          ln2s + (size_t)l * DMODEL, ln2b + (size_t)l * DMODEL, x, xb);
    }
  }

  // logits = x @ emb^T + final_b
  // BM=256 (wave tile 128x64): 42.7 FLOP per LDS byte — raises the ds_read ceiling.
  // 72KB LDS -> 2 blocks/CU; grid 4x250 = 1000 blocks.
  if (mode >= 1) {
    gemm_bt<256, 128, 32, 0, true, false, 0, 1><<<dim3(4, 250), 256, 0, stream>>>(
        xb, DMODEL, embT, DMODEL, finalb, out, NVOCAB, DMODEL);
  } else {
    gemm_bt<128, 128, 32, 1, true, false, 0, 1><<<dim3(8, 250), 256, 0, stream>>>(
        xb, DMODEL, emb, DMODEL, finalb, out, NVOCAB, DMODEL);
  }
}